// Round 8
// baseline (561.542 us; speedup 1.0000x reference)
//
#include <hip/hip_runtime.h>
#include <math.h>

#define N_TOK 32768
#define DIM   512
#define NEXP  64
#define HID   1024
#define CAP   512

typedef float  f32x4  __attribute__((ext_vector_type(4)));
typedef short  bf16x8 __attribute__((ext_vector_type(8)));
typedef unsigned short u16;

#define GET4(v, jj) ((jj) == 0 ? (v).x : (jj) == 1 ? (v).y : (jj) == 2 ? (v).z : (v).w)

__device__ __forceinline__ u16 f2bf(float f) {
  unsigned u = __float_as_uint(f);
  u += 0x7FFFu + ((u >> 16) & 1u);   // RNE
  return (u16)(u >> 16);
}
__device__ __forceinline__ unsigned enc_f(float f) {  // monotone f32 -> u32
  unsigned u = __float_as_uint(f);
  return (u & 0x80000000u) ? ~u : (u | 0x80000000u);
}
__device__ __forceinline__ float dec_f(unsigned k) {
  unsigned u = (k & 0x80000000u) ? (k & 0x7FFFFFFFu) : ~k;
  return __uint_as_float(u);
}
__device__ __forceinline__ void gl16(const u16* g, u16* l) {
  __builtin_amdgcn_global_load_lds(
      (const __attribute__((address_space(1))) unsigned int*)g,
      (__attribute__((address_space(3))) unsigned int*)l, 16, 0, 0);
}

// ---------------- router ----------------
__global__ __launch_bounds__(256)
void router_kernel(const float* __restrict__ x, const float* __restrict__ rw,
                   float* __restrict__ logitsT) {
  const int t = threadIdx.x;
  const int n0 = blockIdx.x * 32 + (t >> 4) * 2;
  const int e0 = (t & 15) * 4;
  float acc[8];
#pragma unroll
  for (int i = 0; i < 8; ++i) acc[i] = 0.f;
  const float* xr0 = x + (size_t)(n0 + 0) * DIM;
  const float* xr1 = x + (size_t)(n0 + 1) * DIM;
  for (int k0 = 0; k0 < DIM; k0 += 4) {
    float4 a0 = *(const float4*)(xr0 + k0);
    float4 a1 = *(const float4*)(xr1 + k0);
#pragma unroll
    for (int kk = 0; kk < 4; ++kk) {
      float4 b = *(const float4*)(rw + (size_t)(k0 + kk) * NEXP + e0);
      float d0 = GET4(a0, kk);
      float d1 = GET4(a1, kk);
      acc[0] += d0 * b.x; acc[1] += d0 * b.y; acc[2] += d0 * b.z; acc[3] += d0 * b.w;
      acc[4] += d1 * b.x; acc[5] += d1 * b.y; acc[6] += d1 * b.z; acc[7] += d1 * b.w;
    }
  }
#pragma unroll
  for (int j = 0; j < 2; ++j)
#pragma unroll
    for (int ee = 0; ee < 4; ++ee)
      logitsT[(size_t)(e0 + ee) * N_TOK + (n0 + j)] = acc[j * 4 + ee];
}

// ------------- topk -------------
__global__ __launch_bounds__(1024)
void topk_kernel(const float* __restrict__ logitsT, int* __restrict__ tok_idx,
                 float* __restrict__ expw, float* __restrict__ auxout) {
  const int e = blockIdx.x;
  const int t = threadIdx.x;
  const float* row = logitsT + (size_t)e * N_TOK;

  unsigned key[32];          // token n = j*1024 + t
#pragma unroll
  for (int j = 0; j < 32; ++j) key[j] = enc_f(row[j * 1024 + t]);

  __shared__ unsigned ured[1024];
  __shared__ float    fred[1024];
  __shared__ unsigned hist[256];
  __shared__ unsigned sh_chosen, sh_rem, sh_x, sh_pos;

  unsigned km = 0;
#pragma unroll
  for (int j = 0; j < 32; ++j) km = key[j] > km ? key[j] : km;
  ured[t] = km;
  __syncthreads();
  for (int s = 512; s > 0; s >>= 1) {
    if (t < s) { unsigned o = ured[t + s]; if (o > ured[t]) ured[t] = o; }
    __syncthreads();
  }
  const float m = dec_f(ured[0]);

  float ssum = 0.f;
#pragma unroll
  for (int j = 0; j < 32; ++j) ssum += expf(dec_f(key[j]) - m);
  fred[t] = ssum;
  __syncthreads();
  for (int s = 512; s > 0; s >>= 1) {
    if (t < s) fred[t] += fred[t + s];
    __syncthreads();
  }
  const float invZ = 1.0f / fred[0];

  if (t == 0) sh_rem = CAP;
  __syncthreads();
  unsigned live = 0xFFFFFFFFu;
  unsigned prefix = 0;
  for (int pass = 0; pass < 4; ++pass) {
    const int shift = 24 - pass * 8;
    if (t < 256) hist[t] = 0;
    __syncthreads();
#pragma unroll
    for (int j = 0; j < 32; ++j)
      if (live & (1u << j)) atomicAdd(&hist[(key[j] >> shift) & 0xFFu], 1u);
    __syncthreads();
    if (t == 0) {
      unsigned need = sh_rem, accum = 0;
      int found = 0;
      for (int b = 255; b >= 0; --b) {
        unsigned cn = hist[b];
        if (!found) {
          if (accum + cn >= need) { sh_chosen = (unsigned)b; sh_rem = need - accum; found = 1; }
          else accum += cn;
        }
      }
    }
    __syncthreads();
    const unsigned ch = sh_chosen;
#pragma unroll
    for (int j = 0; j < 32; ++j)
      if (((key[j] >> shift) & 0xFFu) != ch) live &= ~(1u << j);
    prefix = (prefix << 8) | ch;
    __syncthreads();
  }
  const unsigned ustar = prefix;

  if (t == 0) sh_pos = 0;
  __syncthreads();
#pragma unroll
  for (int j = 0; j < 32; ++j) {
    if (key[j] > ustar) {
      unsigned p = atomicAdd(&sh_pos, 1u);
      tok_idx[e * CAP + p] = j * 1024 + t;
      expw[e * CAP + p] = expf(dec_f(key[j]) - m) * invZ;
    }
  }
  __syncthreads();
  const unsigned padv = CAP - sh_pos;

  if (t < 256) hist[t] = 0;
  __syncthreads();
#pragma unroll
  for (int j = 0; j < 32; ++j)
    if (live & (1u << j)) atomicAdd(&hist[(j * 1024 + t) >> 7], 1u);
  __syncthreads();
  if (t == 0) {
    unsigned accum = 0;
    int found = 0;
    for (int b = 0; b < 256; ++b) {
      unsigned cn = hist[b];
      if (!found) {
        if (accum + cn >= padv) { sh_chosen = (unsigned)b; sh_rem = padv - accum; found = 1; }
        else accum += cn;
      }
    }
  }
  __syncthreads();
  const unsigned hb = sh_chosen, rem = sh_rem;
  if (t < 256) hist[t] = 0;
  __syncthreads();
#pragma unroll
  for (int j = 0; j < 32; ++j)
    if (live & (1u << j)) {
      int n = j * 1024 + t;
      if ((unsigned)(n >> 7) == hb) atomicAdd(&hist[n & 127], 1u);
    }
  __syncthreads();
  if (t == 0) {
    unsigned accum = 0;
    int found = 0;
    for (int b = 0; b < 128; ++b) {
      unsigned cn = hist[b];
      if (!found) {
        if (accum + cn >= rem) { sh_x = (hb << 7) | (unsigned)b; found = 1; }
        else accum += cn;
      }
    }
  }
  __syncthreads();
  const int X = (int)sh_x;
#pragma unroll
  for (int j = 0; j < 32; ++j)
    if (live & (1u << j)) {
      int n = j * 1024 + t;
      if (n <= X) {
        unsigned p = atomicAdd(&sh_pos, 1u);
        tok_idx[e * CAP + p] = n;
        expw[e * CAP + p] = expf(dec_f(key[j]) - m) * invZ;
      }
    }
  if (e == 0 && t == 0) { auxout[0] = 2.44140625e-4f; auxout[1] = 0.015625f; }
}

// ---------------- prep: f32 -> bf16 cast ----------------
__global__ __launch_bounds__(256)
void cvt_bf16_kernel(const float* __restrict__ in, u16* __restrict__ outp) {
  size_t i = ((size_t)blockIdx.x * 256 + threadIdx.x) * 8;
  float4 v0 = *(const float4*)(in + i);
  float4 v1 = *(const float4*)(in + i + 4);
  uint4 o;
  o.x = f2bf(v0.x) | ((unsigned)f2bf(v0.y) << 16);
  o.y = f2bf(v0.z) | ((unsigned)f2bf(v0.w) << 16);
  o.z = f2bf(v1.x) | ((unsigned)f2bf(v1.y) << 16);
  o.w = f2bf(v1.z) | ((unsigned)f2bf(v1.w) << 16);
  *(uint4*)(outp + i) = o;
}

// ---------------- prep: per-expert transpose+cvt: f32 [E][R][C] -> bf16 [E][C][R] ----------------
__global__ __launch_bounds__(256)
void transpose_cvt_kernel(const float* __restrict__ in, u16* __restrict__ outp,
                          int R, int C) {
  __shared__ u16 tile[64][66];
  const int e = blockIdx.z;
  const int r0 = blockIdx.y * 64, c0 = blockIdx.x * 64;
  const int t = threadIdx.x;
  {
    const int r = t >> 2, cs = (t & 3) * 16;
    const float* ip = in + ((size_t)e * R + (r0 + r)) * C + c0 + cs;
#pragma unroll
    for (int q = 0; q < 4; ++q) {
      float4 v = *(const float4*)(ip + q * 4);
      tile[r][cs + q * 4 + 0] = f2bf(v.x);
      tile[r][cs + q * 4 + 1] = f2bf(v.y);
      tile[r][cs + q * 4 + 2] = f2bf(v.z);
      tile[r][cs + q * 4 + 3] = f2bf(v.w);
    }
  }
  __syncthreads();
  {
    const int c = t >> 2, rs = (t & 3) * 16;
    u16* op = outp + ((size_t)e * C + (c0 + c)) * R + r0 + rs;
    uint4 o0, o1;
    o0.x = tile[rs + 0][c]  | ((unsigned)tile[rs + 1][c]  << 16);
    o0.y = tile[rs + 2][c]  | ((unsigned)tile[rs + 3][c]  << 16);
    o0.z = tile[rs + 4][c]  | ((unsigned)tile[rs + 5][c]  << 16);
    o0.w = tile[rs + 6][c]  | ((unsigned)tile[rs + 7][c]  << 16);
    o1.x = tile[rs + 8][c]  | ((unsigned)tile[rs + 9][c]  << 16);
    o1.y = tile[rs + 10][c] | ((unsigned)tile[rs + 11][c] << 16);
    o1.z = tile[rs + 12][c] | ((unsigned)tile[rs + 13][c] << 16);
    o1.w = tile[rs + 14][c] | ((unsigned)tile[rs + 15][c] << 16);
    *(uint4*)(op) = o0;
    *(uint4*)(op + 8) = o1;
  }
}

// ===================== bf16 GEMMs: 256x256 tile, 8 waves, dbuf, global_load_lds =====================
// Per wave output 128x64 (acc[8][4]); stage 4 A-chunks + 4 B-chunks (8 gl16) per K-step.
__device__ __forceinline__ void gemm256(const u16* As, const u16* Bs,
                                        int wm, int wn, int lr, int hi4,
                                        f32x4 acc[8][4]) {
#pragma unroll
  for (int ks = 0; ks < 2; ++ks) {
    const int kb = ks * 64 + hi4 * 16;
    bf16x8 bf[4];
#pragma unroll
    for (int ni = 0; ni < 4; ++ni) {
      const int row = wn * 64 + ni * 16 + lr;
      bf[ni] = *(const bf16x8*)((const char*)Bs + row * 128 + (kb ^ ((row & 7) << 4)));
    }
#pragma unroll
    for (int mi = 0; mi < 8; ++mi) {
      const int row = wm * 128 + mi * 16 + lr;
      bf16x8 af = *(const bf16x8*)((const char*)As + row * 128 + (kb ^ ((row & 7) << 4)));
#pragma unroll
      for (int ni = 0; ni < 4; ++ni)
        acc[mi][ni] = __builtin_amdgcn_mfma_f32_16x16x32_bf16(af, bf[ni], acc[mi][ni], 0, 0, 0);
    }
  }
}

__global__ __launch_bounds__(512, 2)
void fc1_bf(const u16* __restrict__ xb, const int* __restrict__ tok_idx,
            const u16* __restrict__ w1t, const float* __restrict__ b1,
            u16* __restrict__ h) {
  const int p = blockIdx.x;
  const int l = (p & 7) * 64 + (p >> 3);         // bijective XCD remap (512 = 8*64)
  const int e  = l >> 3;
  const int mt = (l >> 2) & 1;
  const int nt = l & 3;
  const int m0 = mt * 256, n0 = nt * 256;
  const int t = threadIdx.x;
  const int lane = t & 63, wave = t >> 6;        // 8 waves
  const int wm = wave >> 2, wn = wave & 3;       // 2 x 4

  __shared__ __align__(16) u16 Asm[2][256 * 64];  // 64 KB
  __shared__ __align__(16) u16 Bsm[2][256 * 64];  // 64 KB

  const int gk = ((lane & 7) ^ (lane >> 3)) * 8; // inverse-swizzled k elem offset
  const int rsub = lane >> 3;

  const u16* aS[4]; const u16* bS[4];
  int dOff[4];
#pragma unroll
  for (int i = 0; i < 4; ++i) {
    const int chunk = wave * 4 + i;               // 0..31
    const int arow = chunk * 8 + rsub;            // 0..255
    const int tok = tok_idx[e * CAP + m0 + arow];
    aS[i] = xb + (size_t)tok * DIM + gk;
    bS[i] = w1t + ((size_t)e * HID + n0 + arow) * DIM + gk;
    dOff[i] = chunk * 512;
  }

  f32x4 acc[8][4] = {};
  const int lr = lane & 15, hi4 = lane >> 4;

#define STAGE1(buf, k0) do { \
  _Pragma("unroll") \
  for (int i = 0; i < 4; ++i) { \
    gl16(aS[i] + (k0), &Asm[buf][dOff[i]]); \
    gl16(bS[i] + (k0), &Bsm[buf][dOff[i]]); \
  } } while (0)

  STAGE1(0, 0);
  asm volatile("s_waitcnt vmcnt(0)" ::: "memory");
  __builtin_amdgcn_s_barrier();
#pragma unroll
  for (int tt = 0; tt < 7; ++tt) {                // DIM/64 - 1
    const int cur = tt & 1;
    STAGE1(cur ^ 1, (tt + 1) * 64);
    gemm256(Asm[cur], Bsm[cur], wm, wn, lr, hi4, acc);
    asm volatile("s_waitcnt vmcnt(0)" ::: "memory");
    __builtin_amdgcn_s_barrier();
  }
  gemm256(Asm[1], Bsm[1], wm, wn, lr, hi4, acc);

  const int lq = lane >> 4, lc = lane & 15;
#pragma unroll
  for (int ni = 0; ni < 4; ++ni) {
    const int n_l = wn * 64 + ni * 16 + lc;
    const float bias = b1[e * HID + n0 + n_l];
#pragma unroll
    for (int mi = 0; mi < 8; ++mi) {
#pragma unroll
      for (int j = 0; j < 4; ++j) {
        const int m_l = wm * 128 + mi * 16 + lq * 4 + j;
        float v = acc[mi][ni][j] + bias;
        float gv = 0.5f * v * (1.0f + erff(v * 0.70710678118654752f));
        h[((size_t)(e * CAP + m0 + m_l)) * HID + (n0 + n_l)] = f2bf(gv);
      }
    }
  }
}

__global__ __launch_bounds__(512, 2)
void fc2_bf(const u16* __restrict__ h, const u16* __restrict__ w2t,
            const float* __restrict__ b2, const int* __restrict__ tok_idx,
            const float* __restrict__ expw, float* __restrict__ out) {
  const int p = blockIdx.x;
  const int l = (p & 7) * 32 + (p >> 3);         // bijective XCD remap (256 = 8*32)
  const int e  = l >> 2;
  const int mt = (l >> 1) & 1;
  const int nt = l & 1;
  const int m0 = mt * 256, n0 = nt * 256;
  const int t = threadIdx.x;
  const int lane = t & 63, wave = t >> 6;
  const int wm = wave >> 2, wn = wave & 3;

  __shared__ __align__(16) u16 Asm[2][256 * 64];
  __shared__ __align__(16) u16 Bsm[2][256 * 64];

  const int gk = ((lane & 7) ^ (lane >> 3)) * 8;
  const int rsub = lane >> 3;

  const u16* aS[4]; const u16* bS[4];
  int dOff[4];
#pragma unroll
  for (int i = 0; i < 4; ++i) {
    const int chunk = wave * 4 + i;
    const int arow = chunk * 8 + rsub;
    aS[i] = h + ((size_t)(e * CAP + m0 + arow)) * HID + gk;
    bS[i] = w2t + ((size_t)e * DIM + n0 + arow) * HID + gk;
    dOff[i] = chunk * 512;
  }

  f32x4 acc[8][4] = {};
  const int lr = lane & 15, hi4 = lane >> 4;

#define STAGE2(buf, k0) do { \
  _Pragma("unroll") \
  for (int i = 0; i < 4; ++i) { \
    gl16(aS[i] + (k0), &Asm[buf][dOff[i]]); \
    gl16(bS[i] + (k0), &Bsm[buf][dOff[i]]); \
  } } while (0)

  STAGE2(0, 0);
  asm volatile("s_waitcnt vmcnt(0)" ::: "memory");
  __builtin_amdgcn_s_barrier();
#pragma unroll 1
  for (int tt = 0; tt < 15; ++tt) {               // HID/64 - 1
    const int cur = tt & 1;
    STAGE2(cur ^ 1, (tt + 1) * 64);
    gemm256(Asm[cur], Bsm[cur], wm, wn, lr, hi4, acc);
    asm volatile("s_waitcnt vmcnt(0)" ::: "memory");
    __builtin_amdgcn_s_barrier();
  }
  gemm256(Asm[1], Bsm[1], wm, wn, lr, hi4, acc);

  const int lq = lane >> 4, lc = lane & 15;
#pragma unroll
  for (int mi = 0; mi < 8; ++mi) {
#pragma unroll
    for (int j = 0; j < 4; ++j) {
      const int m_l = wm * 128 + mi * 16 + lq * 4 + j;
      const int tok = tok_idx[e * CAP + m0 + m_l];
      const float wgt = expw[e * CAP + m0 + m_l];
#pragma unroll
      for (int ni = 0; ni < 4; ++ni) {
        const int n_l = wn * 64 + ni * 16 + lc;
        float v = (acc[mi][ni][j] + b2[e * DIM + n0 + n_l]) * wgt;
        atomicAdd(out + (size_t)tok * DIM + (n0 + n_l), v);
      }
    }
  }
}

// ===================== fallback f32-input GEMMs (ws too small) =====================
#define SWZ(row, cb) ((cb) ^ (((((row) >> 3) ^ (row)) & 7) << 4))

__global__ __launch_bounds__(256)
void fc1_kernel(const float* __restrict__ x, const int* __restrict__ tok_idx,
                const float* __restrict__ w1, const float* __restrict__ b1,
                u16* __restrict__ h) {
  const int bx = blockIdx.x;
  const int e  = bx >> 5;
  const int mt = (bx >> 3) & 3;
  const int nt = bx & 7;
  const int m0 = mt * 128, n0 = nt * 128;
  const int t = threadIdx.x;
  const int lane = t & 63, wave = t >> 6;
  const int wm = wave >> 1, wn = wave & 1;

  __shared__ __align__(16) u16 Asm[128 * 64];
  __shared__ __align__(16) u16 Bsm[128 * 64];

  const int arq = t & 31, akq = t >> 5;
  int tokr[4];
#pragma unroll
  for (int j = 0; j < 4; ++j) tokr[j] = tok_idx[e * CAP + m0 + arq * 4 + j];
  const int nq = t & 31, kq = t >> 5;
  const float* bptr = w1 + (size_t)e * DIM * HID + n0 + nq * 4;

  f32x4 acc[4][4] = {};

  for (int k0 = 0; k0 < DIM; k0 += 64) {
    float4 av0[4], av1[4];
#pragma unroll
    for (int j = 0; j < 4; ++j) {
      const float* ap = x + (size_t)tokr[j] * DIM + k0 + akq * 8;
      av0[j] = *(const float4*)(ap);
      av1[j] = *(const float4*)(ap + 4);
    }
    float4 bv[8];
#pragma unroll
    for (int kk = 0; kk < 8; ++kk)
      bv[kk] = *(const float4*)(bptr + (size_t)(k0 + kq * 8 + kk) * HID);
    __syncthreads();
#pragma unroll
    for (int j = 0; j < 4; ++j) {
      const int row = arq * 4 + j;
      ushort4 w0, w1v;
      w0.x = f2bf(av0[j].x); w0.y = f2bf(av0[j].y); w0.z = f2bf(av0[j].z); w0.w = f2bf(av0[j].w);
      w1v.x = f2bf(av1[j].x); w1v.y = f2bf(av1[j].y); w1v.z = f2bf(av1[j].z); w1v.w = f2bf(av1[j].w);
      *(ushort4*)((char*)Asm + row * 128 + SWZ(row, (akq * 8 + 0) * 2)) = w0;
      *(ushort4*)((char*)Asm + row * 128 + SWZ(row, (akq * 8 + 4) * 2)) = w1v;
    }
#pragma unroll
    for (int g = 0; g < 2; ++g) {
#pragma unroll
      for (int j = 0; j < 4; ++j) {
        ushort4 wv;
        wv.x = f2bf(GET4(bv[g * 4 + 0], j));
        wv.y = f2bf(GET4(bv[g * 4 + 1], j));
        wv.z = f2bf(GET4(bv[g * 4 + 2], j));
        wv.w = f2bf(GET4(bv[g * 4 + 3], j));
        const int row = nq * 4 + j;
        const int cb = (kq * 8 + g * 4) * 2;
        *(ushort4*)((char*)Bsm + row * 128 + SWZ(row, cb)) = wv;
      }
    }
    __syncthreads();
#pragma unroll
    for (int ks = 0; ks < 2; ++ks) {
      bf16x8 af[4], bf[4];
#pragma unroll
      for (int mi = 0; mi < 4; ++mi) {
        const int row = wm * 64 + mi * 16 + (lane & 15);
        const int cb = ks * 64 + (lane >> 4) * 16;
        af[mi] = *(const bf16x8*)((const char*)Asm + row * 128 + SWZ(row, cb));
      }
#pragma unroll
      for (int ni = 0; ni < 4; ++ni) {
        const int row = wn * 64 + ni * 16 + (lane & 15);
        const int cb = ks * 64 + (lane >> 4) * 16;
        bf[ni] = *(const bf16x8*)((const char*)Bsm + row * 128 + SWZ(row, cb));
      }
#pragma unroll
      for (int mi = 0; mi < 4; ++mi)
#pragma unroll
        for (int ni = 0; ni < 4; ++ni)
          acc[mi][ni] = __builtin_amdgcn_mfma_f32_16x16x32_bf16(af[mi], bf[ni], acc[mi][ni], 0, 0, 0);
    }
  }
  const int lq = lane >> 4, lc = lane & 15;
#pragma unroll
  for (int ni = 0; ni < 4; ++ni) {
    const int n_l = wn * 64 + ni * 16 + lc;
    const float bias = b1[e * HID + n0 + n_l];
#pragma unroll
    for (int mi = 0; mi < 4; ++mi) {
#pragma unroll
      for (int j = 0; j < 4; ++j) {
        const int m_l = wm * 64 + mi * 16 + lq * 4 + j;
        float v = acc[mi][ni][j] + bias;
        float gv = 0.5f * v * (1.0f + erff(v * 0.70710678118654752f));
        h[((size_t)(e * CAP + m0 + m_l)) * HID + (n0 + n_l)] = f2bf(gv);
      }
    }
  }
}

__global__ __launch_bounds__(256)
void fc2_kernel(const u16* __restrict__ h, const float* __restrict__ w2,
                const float* __restrict__ b2, const int* __restrict__ tok_idx,
                const float* __restrict__ expw, float* __restrict__ out) {
  const int bx = blockIdx.x;
  const int e  = bx >> 4;
  const int mt = (bx >> 2) & 3;
  const int nt = bx & 3;
  const int m0 = mt * 128, n0 = nt * 128;
  const int t = threadIdx.x;
  const int lane = t & 63, wave = t >> 6;
  const int wm = wave >> 1, wn = wave & 1;

  __shared__ __align__(16) u16 Asm[128 * 64];
  __shared__ __align__(16) u16 Bsm[128 * 64];

  const int arq = t & 31, akq = t >> 5;
  const u16* aptr0 = h + ((size_t)(e * CAP + m0 + arq * 4)) * HID + akq * 8;
  const int nq = t & 31, kq = t >> 5;
  const float* bptr = w2 + (size_t)e * HID * DIM + n0 + nq * 4;

  f32x4 acc[4][4] = {};

  for (int k0 = 0; k0 < HID; k0 += 64) {
    uint4 av[4];
#pragma unroll
    for (int j = 0; j < 4; ++j)
      av[j] = *(const uint4*)(aptr0 + (size_t)j * HID + k0);
    float4 bv[8];
#pragma unroll
    for (int kk = 0; kk < 8; ++kk)
      bv[kk] = *(const float4*)(bptr + (size_t)(k0 + kq * 8 + kk) * DIM);
    __syncthreads();
#pragma unroll
    for (int j = 0; j < 4; ++j) {
      const int row = arq * 4 + j;
      *(uint4*)((char*)Asm + row * 128 + SWZ(row, akq * 16)) = av[j];
    }
#pragma unroll
    for (int g = 0; g < 2; ++g) {
#pragma unroll
      for (int j = 0; j < 4; ++j) {
        ushort4 wv;
        wv.x = f2bf(GET4(bv[g * 4 + 0], j));
        wv.y = f2bf(GET4(bv[g * 4 + 1], j));
        wv.z = f2bf(GET4(bv[g * 4 + 2], j));
        wv.w = f2bf(GET4(bv[g * 4 + 3], j));
        const int row = nq * 4 + j;
        const int cb = (kq * 8 + g * 4) * 2;
        *(ushort4*)((char*)Bsm + row * 128 + SWZ(row, cb)) = wv;
      }
    }
    __syncthreads();
#pragma unroll
    for (int ks = 0; ks < 2; ++ks) {
      bf16x8 af[4], bf[4];
#pragma unroll
      for (int mi = 0; mi < 4; ++mi) {
        const int row = wm * 64 + mi * 16 + (lane & 15);
        const int cb = ks * 64 + (lane >> 4) * 16;
        af[mi] = *(const bf16x8*)((const char*)Asm + row * 128 + SWZ(row, cb));
      }
#pragma unroll
      for (int ni = 0; ni < 4; ++ni) {
        const int row = wn * 64 + ni * 16 + (lane & 15);
        const int cb = ks * 64 + (lane >> 4) * 16;
        bf[ni] = *(const bf16x8*)((const char*)Bsm + row * 128 + SWZ(row, cb));
      }
#pragma unroll
      for (int mi = 0; mi < 4; ++mi)
#pragma unroll
        for (int ni = 0; ni < 4; ++ni)
          acc[mi][ni] = __builtin_amdgcn_mfma_f32_16x16x32_bf16(af[mi], bf[ni], acc[mi][ni], 0, 0, 0);
    }
  }
  const int lq = lane >> 4, lc = lane & 15;
  int   tokm[4][4];
  float wgt[4][4];
#pragma unroll
  for (int mi = 0; mi < 4; ++mi)
#pragma unroll
    for (int j = 0; j < 4; ++j) {
      const int m_l = wm * 64 + mi * 16 + lq * 4 + j;
      tokm[mi][j] = tok_idx[e * CAP + m0 + m_l];
      wgt[mi][j]  = expw[e * CAP + m0 + m_l];
    }
#pragma unroll
  for (int ni = 0; ni < 4; ++ni) {
    const int n_l = wn * 64 + ni * 16 + lc;
    const float bias = b2[e * DIM + n0 + n_l];
#pragma unroll
    for (int mi = 0; mi < 4; ++mi)
#pragma unroll
      for (int j = 0; j < 4; ++j) {
        float v = (acc[mi][ni][j] + bias) * wgt[mi][j];
        atomicAdd(out + (size_t)tokm[mi][j] * DIM + (n0 + n_l), v);
      }
  }
}

extern "C" void kernel_launch(void* const* d_in, const int* in_sizes, int n_in,
                              void* d_out, int out_size, void* d_ws, size_t ws_size,
                              hipStream_t stream) {
  const float* x  = (const float*)d_in[0];
  const float* rw = (const float*)d_in[1];
  const float* w1 = (const float*)d_in[2];
  const float* b1 = (const float*)d_in[3];
  const float* w2 = (const float*)d_in[4];
  const float* b2 = (const float*)d_in[5];
  float* out = (float*)d_out;

  char* ws = (char*)d_ws;
  const size_t MB = 1u << 20;
  float* logits = (float*)ws;                                   // [0, 8M)
  int*   toki   = (int*)(ws + 8 * MB);                          // 128 KB
  float* ew     = (float*)(ws + 8 * MB + (128u << 10));         // 128 KB

  (void)hipMemsetAsync(d_out, 0, (size_t)out_size * sizeof(float), stream);
  router_kernel<<<dim3(1024), dim3(256), 0, stream>>>(x, rw, logits);
  topk_kernel<<<dim3(64), dim3(1024), 0, stream>>>(logits, toki, ew, out + (size_t)N_TOK * DIM);

  const size_t off_xb = 8 * MB + (256u << 10);   // 8.25M
  const size_t off_wt = off_xb + 32 * MB;        // 40.25M
  const size_t off_h  = off_wt + 64 * MB;        // 104.25M
  const size_t need   = off_h + 64 * MB;         // 168.25M

  if (ws_size >= need) {
    u16* xb  = (u16*)(ws + off_xb);
    u16* wt  = (u16*)(ws + off_wt);
    u16* h   = (u16*)(ws + off_h);
    cvt_bf16_kernel<<<dim3(8192), dim3(256), 0, stream>>>(x, xb);
    transpose_cvt_kernel<<<dim3(16, 8, 64), dim3(256), 0, stream>>>(w1, wt, 512, 1024);
    fc1_bf<<<dim3(512), dim3(512), 0, stream>>>(xb, toki, wt, b1, h);
    transpose_cvt_kernel<<<dim3(8, 16, 64), dim3(256), 0, stream>>>(w2, wt, 1024, 512);
    fc2_bf<<<dim3(256), dim3(512), 0, stream>>>(h, wt, b2, toki, ew, out);
  } else {
    u16* h = (u16*)(ws + 8 * MB + (256u << 10)); // old layout
    fc1_kernel<<<dim3(2048), dim3(256), 0, stream>>>(x, toki, w1, b1, h);
    fc2_kernel<<<dim3(1024), dim3(256), 0, stream>>>(h, w2, b2, toki, ew, out);
  }
}

// Round 9
// 560.751 us; speedup vs baseline: 1.0014x; 1.0014x over previous
//
#include <hip/hip_runtime.h>
#include <math.h>

#define N_TOK 32768
#define DIM   512
#define NEXP  64
#define HID   1024
#define CAP   512

typedef float  f32x4  __attribute__((ext_vector_type(4)));
typedef short  bf16x8 __attribute__((ext_vector_type(8)));
typedef unsigned short u16;

#define GET4(v, jj) ((jj) == 0 ? (v).x : (jj) == 1 ? (v).y : (jj) == 2 ? (v).z : (v).w)

__device__ __forceinline__ u16 f2bf(float f) {
  unsigned u = __float_as_uint(f);
  u += 0x7FFFu + ((u >> 16) & 1u);   // RNE
  return (u16)(u >> 16);
}
__device__ __forceinline__ unsigned enc_f(float f) {  // monotone f32 -> u32
  unsigned u = __float_as_uint(f);
  return (u & 0x80000000u) ? ~u : (u | 0x80000000u);
}
__device__ __forceinline__ float dec_f(unsigned k) {
  unsigned u = (k & 0x80000000u) ? (k & 0x7FFFFFFFu) : ~k;
  return __uint_as_float(u);
}
__device__ __forceinline__ void gl16(const u16* g, u16* l) {
  __builtin_amdgcn_global_load_lds(
      (const __attribute__((address_space(1))) unsigned int*)g,
      (__attribute__((address_space(3))) unsigned int*)l, 16, 0, 0);
}

// ---------------- router ----------------
__global__ __launch_bounds__(256)
void router_kernel(const float* __restrict__ x, const float* __restrict__ rw,
                   float* __restrict__ logitsT) {
  const int t = threadIdx.x;
  const int n0 = blockIdx.x * 32 + (t >> 4) * 2;
  const int e0 = (t & 15) * 4;
  float acc[8];
#pragma unroll
  for (int i = 0; i < 8; ++i) acc[i] = 0.f;
  const float* xr0 = x + (size_t)(n0 + 0) * DIM;
  const float* xr1 = x + (size_t)(n0 + 1) * DIM;
  for (int k0 = 0; k0 < DIM; k0 += 4) {
    float4 a0 = *(const float4*)(xr0 + k0);
    float4 a1 = *(const float4*)(xr1 + k0);
#pragma unroll
    for (int kk = 0; kk < 4; ++kk) {
      float4 b = *(const float4*)(rw + (size_t)(k0 + kk) * NEXP + e0);
      float d0 = GET4(a0, kk);
      float d1 = GET4(a1, kk);
      acc[0] += d0 * b.x; acc[1] += d0 * b.y; acc[2] += d0 * b.z; acc[3] += d0 * b.w;
      acc[4] += d1 * b.x; acc[5] += d1 * b.y; acc[6] += d1 * b.z; acc[7] += d1 * b.w;
    }
  }
#pragma unroll
  for (int j = 0; j < 2; ++j)
#pragma unroll
    for (int ee = 0; ee < 4; ++ee)
      logitsT[(size_t)(e0 + ee) * N_TOK + (n0 + j)] = acc[j * 4 + ee];
}

// ------------- topk -------------
__global__ __launch_bounds__(1024)
void topk_kernel(const float* __restrict__ logitsT, int* __restrict__ tok_idx,
                 float* __restrict__ expw, float* __restrict__ auxout) {
  const int e = blockIdx.x;
  const int t = threadIdx.x;
  const float* row = logitsT + (size_t)e * N_TOK;

  unsigned key[32];          // token n = j*1024 + t
#pragma unroll
  for (int j = 0; j < 32; ++j) key[j] = enc_f(row[j * 1024 + t]);

  __shared__ unsigned ured[1024];
  __shared__ float    fred[1024];
  __shared__ unsigned hist[256];
  __shared__ unsigned sh_chosen, sh_rem, sh_x, sh_pos;

  unsigned km = 0;
#pragma unroll
  for (int j = 0; j < 32; ++j) km = key[j] > km ? key[j] : km;
  ured[t] = km;
  __syncthreads();
  for (int s = 512; s > 0; s >>= 1) {
    if (t < s) { unsigned o = ured[t + s]; if (o > ured[t]) ured[t] = o; }
    __syncthreads();
  }
  const float m = dec_f(ured[0]);

  float ssum = 0.f;
#pragma unroll
  for (int j = 0; j < 32; ++j) ssum += expf(dec_f(key[j]) - m);
  fred[t] = ssum;
  __syncthreads();
  for (int s = 512; s > 0; s >>= 1) {
    if (t < s) fred[t] += fred[t + s];
    __syncthreads();
  }
  const float invZ = 1.0f / fred[0];

  if (t == 0) sh_rem = CAP;
  __syncthreads();
  unsigned live = 0xFFFFFFFFu;
  unsigned prefix = 0;
  for (int pass = 0; pass < 4; ++pass) {
    const int shift = 24 - pass * 8;
    if (t < 256) hist[t] = 0;
    __syncthreads();
#pragma unroll
    for (int j = 0; j < 32; ++j)
      if (live & (1u << j)) atomicAdd(&hist[(key[j] >> shift) & 0xFFu], 1u);
    __syncthreads();
    if (t == 0) {
      unsigned need = sh_rem, accum = 0;
      int found = 0;
      for (int b = 255; b >= 0; --b) {
        unsigned cn = hist[b];
        if (!found) {
          if (accum + cn >= need) { sh_chosen = (unsigned)b; sh_rem = need - accum; found = 1; }
          else accum += cn;
        }
      }
    }
    __syncthreads();
    const unsigned ch = sh_chosen;
#pragma unroll
    for (int j = 0; j < 32; ++j)
      if (((key[j] >> shift) & 0xFFu) != ch) live &= ~(1u << j);
    prefix = (prefix << 8) | ch;
    __syncthreads();
  }
  const unsigned ustar = prefix;

  if (t == 0) sh_pos = 0;
  __syncthreads();
#pragma unroll
  for (int j = 0; j < 32; ++j) {
    if (key[j] > ustar) {
      unsigned p = atomicAdd(&sh_pos, 1u);
      tok_idx[e * CAP + p] = j * 1024 + t;
      expw[e * CAP + p] = expf(dec_f(key[j]) - m) * invZ;
    }
  }
  __syncthreads();
  const unsigned padv = CAP - sh_pos;

  if (t < 256) hist[t] = 0;
  __syncthreads();
#pragma unroll
  for (int j = 0; j < 32; ++j)
    if (live & (1u << j)) atomicAdd(&hist[(j * 1024 + t) >> 7], 1u);
  __syncthreads();
  if (t == 0) {
    unsigned accum = 0;
    int found = 0;
    for (int b = 0; b < 256; ++b) {
      unsigned cn = hist[b];
      if (!found) {
        if (accum + cn >= padv) { sh_chosen = (unsigned)b; sh_rem = padv - accum; found = 1; }
        else accum += cn;
      }
    }
  }
  __syncthreads();
  const unsigned hb = sh_chosen, rem = sh_rem;
  if (t < 256) hist[t] = 0;
  __syncthreads();
#pragma unroll
  for (int j = 0; j < 32; ++j)
    if (live & (1u << j)) {
      int n = j * 1024 + t;
      if ((unsigned)(n >> 7) == hb) atomicAdd(&hist[n & 127], 1u);
    }
  __syncthreads();
  if (t == 0) {
    unsigned accum = 0;
    int found = 0;
    for (int b = 0; b < 128; ++b) {
      unsigned cn = hist[b];
      if (!found) {
        if (accum + cn >= rem) { sh_x = (hb << 7) | (unsigned)b; found = 1; }
        else accum += cn;
      }
    }
  }
  __syncthreads();
  const int X = (int)sh_x;
#pragma unroll
  for (int j = 0; j < 32; ++j)
    if (live & (1u << j)) {
      int n = j * 1024 + t;
      if (n <= X) {
        unsigned p = atomicAdd(&sh_pos, 1u);
        tok_idx[e * CAP + p] = n;
        expw[e * CAP + p] = expf(dec_f(key[j]) - m) * invZ;
      }
    }
  if (e == 0 && t == 0) { auxout[0] = 2.44140625e-4f; auxout[1] = 0.015625f; }
}

// ---------------- prep: f32 -> bf16 cast ----------------
__global__ __launch_bounds__(256)
void cvt_bf16_kernel(const float* __restrict__ in, u16* __restrict__ outp) {
  size_t i = ((size_t)blockIdx.x * 256 + threadIdx.x) * 8;
  float4 v0 = *(const float4*)(in + i);
  float4 v1 = *(const float4*)(in + i + 4);
  uint4 o;
  o.x = f2bf(v0.x) | ((unsigned)f2bf(v0.y) << 16);
  o.y = f2bf(v0.z) | ((unsigned)f2bf(v0.w) << 16);
  o.z = f2bf(v1.x) | ((unsigned)f2bf(v1.y) << 16);
  o.w = f2bf(v1.z) | ((unsigned)f2bf(v1.w) << 16);
  *(uint4*)(outp + i) = o;
}

// ---------------- prep: per-expert transpose+cvt: f32 [E][R][C] -> bf16 [E][C][R] ----------------
__global__ __launch_bounds__(256)
void transpose_cvt_kernel(const float* __restrict__ in, u16* __restrict__ outp,
                          int R, int C) {
  __shared__ u16 tile[64][66];
  const int e = blockIdx.z;
  const int r0 = blockIdx.y * 64, c0 = blockIdx.x * 64;
  const int t = threadIdx.x;
  {
    const int r = t >> 2, cs = (t & 3) * 16;
    const float* ip = in + ((size_t)e * R + (r0 + r)) * C + c0 + cs;
#pragma unroll
    for (int q = 0; q < 4; ++q) {
      float4 v = *(const float4*)(ip + q * 4);
      tile[r][cs + q * 4 + 0] = f2bf(v.x);
      tile[r][cs + q * 4 + 1] = f2bf(v.y);
      tile[r][cs + q * 4 + 2] = f2bf(v.z);
      tile[r][cs + q * 4 + 3] = f2bf(v.w);
    }
  }
  __syncthreads();
  {
    const int c = t >> 2, rs = (t & 3) * 16;
    u16* op = outp + ((size_t)e * C + (c0 + c)) * R + r0 + rs;
    uint4 o0, o1;
    o0.x = tile[rs + 0][c]  | ((unsigned)tile[rs + 1][c]  << 16);
    o0.y = tile[rs + 2][c]  | ((unsigned)tile[rs + 3][c]  << 16);
    o0.z = tile[rs + 4][c]  | ((unsigned)tile[rs + 5][c]  << 16);
    o0.w = tile[rs + 6][c]  | ((unsigned)tile[rs + 7][c]  << 16);
    o1.x = tile[rs + 8][c]  | ((unsigned)tile[rs + 9][c]  << 16);
    o1.y = tile[rs + 10][c] | ((unsigned)tile[rs + 11][c] << 16);
    o1.z = tile[rs + 12][c] | ((unsigned)tile[rs + 13][c] << 16);
    o1.w = tile[rs + 14][c] | ((unsigned)tile[rs + 15][c] << 16);
    *(uint4*)(op) = o0;
    *(uint4*)(op + 8) = o1;
  }
}

// ===================== bf16 GEMMs: 256x256 tile, 8 waves, dbuf, global_load_lds =====================
// Per wave output 128x64 (acc[8][4]); stage 4 A-chunks + 4 B-chunks (8 gl16) per K-step.
__device__ __forceinline__ void gemm256(const u16* As, const u16* Bs,
                                        int wm, int wn, int lr, int hi4,
                                        f32x4 acc[8][4]) {
#pragma unroll
  for (int ks = 0; ks < 2; ++ks) {
    const int kb = ks * 64 + hi4 * 16;
    bf16x8 bf[4];
#pragma unroll
    for (int ni = 0; ni < 4; ++ni) {
      const int row = wn * 64 + ni * 16 + lr;
      bf[ni] = *(const bf16x8*)((const char*)Bs + row * 128 + (kb ^ ((row & 7) << 4)));
    }
#pragma unroll
    for (int mi = 0; mi < 8; ++mi) {
      const int row = wm * 128 + mi * 16 + lr;
      bf16x8 af = *(const bf16x8*)((const char*)As + row * 128 + (kb ^ ((row & 7) << 4)));
#pragma unroll
      for (int ni = 0; ni < 4; ++ni)
        acc[mi][ni] = __builtin_amdgcn_mfma_f32_16x16x32_bf16(af, bf[ni], acc[mi][ni], 0, 0, 0);
    }
  }
}

__global__ __launch_bounds__(512, 2)
void fc1_bf(const u16* __restrict__ xb, const int* __restrict__ tok_idx,
            const u16* __restrict__ w1t, const float* __restrict__ b1,
            u16* __restrict__ h) {
  const int p = blockIdx.x;
  const int l = (p & 7) * 64 + (p >> 3);         // bijective XCD remap (512 = 8*64)
  const int e  = l >> 3;
  const int mt = (l >> 2) & 1;
  const int nt = l & 3;
  const int m0 = mt * 256, n0 = nt * 256;
  const int t = threadIdx.x;
  const int lane = t & 63, wave = t >> 6;        // 8 waves
  const int wm = wave >> 2, wn = wave & 3;       // 2 x 4

  __shared__ __align__(16) u16 Asm[2][256 * 64];  // 64 KB
  __shared__ __align__(16) u16 Bsm[2][256 * 64];  // 64 KB

  const int gk = ((lane & 7) ^ (lane >> 3)) * 8; // inverse-swizzled k elem offset
  const int rsub = lane >> 3;

  const u16* aS[4]; const u16* bS[4];
  int dOff[4];
#pragma unroll
  for (int i = 0; i < 4; ++i) {
    const int chunk = wave * 4 + i;               // 0..31
    const int arow = chunk * 8 + rsub;            // 0..255
    const int tok = tok_idx[e * CAP + m0 + arow];
    aS[i] = xb + (size_t)tok * DIM + gk;
    bS[i] = w1t + ((size_t)e * HID + n0 + arow) * DIM + gk;
    dOff[i] = chunk * 512;
  }

  f32x4 acc[8][4] = {};
  const int lr = lane & 15, hi4 = lane >> 4;

#define STAGE1(buf, k0) do { \
  _Pragma("unroll") \
  for (int i = 0; i < 4; ++i) { \
    gl16(aS[i] + (k0), &Asm[buf][dOff[i]]); \
    gl16(bS[i] + (k0), &Bsm[buf][dOff[i]]); \
  } } while (0)

  STAGE1(0, 0);
  asm volatile("s_waitcnt vmcnt(0)" ::: "memory");
  __builtin_amdgcn_s_barrier();
#pragma unroll
  for (int tt = 0; tt < 7; ++tt) {                // DIM/64 - 1
    const int cur = tt & 1;
    STAGE1(cur ^ 1, (tt + 1) * 64);
    gemm256(Asm[cur], Bsm[cur], wm, wn, lr, hi4, acc);
    asm volatile("s_waitcnt vmcnt(0)" ::: "memory");
    __builtin_amdgcn_s_barrier();
  }
  gemm256(Asm[1], Bsm[1], wm, wn, lr, hi4, acc);

  const int lq = lane >> 4, lc = lane & 15;
#pragma unroll
  for (int ni = 0; ni < 4; ++ni) {
    const int n_l = wn * 64 + ni * 16 + lc;
    const float bias = b1[e * HID + n0 + n_l];
#pragma unroll
    for (int mi = 0; mi < 8; ++mi) {
#pragma unroll
      for (int j = 0; j < 4; ++j) {
        const int m_l = wm * 128 + mi * 16 + lq * 4 + j;
        float v = acc[mi][ni][j] + bias;
        float gv = 0.5f * v * (1.0f + erff(v * 0.70710678118654752f));
        h[((size_t)(e * CAP + m0 + m_l)) * HID + (n0 + n_l)] = f2bf(gv);
      }
    }
  }
}

__global__ __launch_bounds__(512, 2)
void fc2_bf(const u16* __restrict__ h, const u16* __restrict__ w2t,
            const float* __restrict__ b2, const int* __restrict__ tok_idx,
            const float* __restrict__ expw, float* __restrict__ out) {
  const int p = blockIdx.x;
  const int l = (p & 7) * 32 + (p >> 3);         // bijective XCD remap (256 = 8*32)
  const int e  = l >> 2;
  const int mt = (l >> 1) & 1;
  const int nt = l & 1;
  const int m0 = mt * 256, n0 = nt * 256;
  const int t = threadIdx.x;
  const int lane = t & 63, wave = t >> 6;
  const int wm = wave >> 2, wn = wave & 3;

  __shared__ __align__(16) u16 Asm[2][256 * 64];
  __shared__ __align__(16) u16 Bsm[2][256 * 64];

  const int gk = ((lane & 7) ^ (lane >> 3)) * 8;
  const int rsub = lane >> 3;

  const u16* aS[4]; const u16* bS[4];
  int dOff[4];
#pragma unroll
  for (int i = 0; i < 4; ++i) {
    const int chunk = wave * 4 + i;
    const int arow = chunk * 8 + rsub;
    aS[i] = h + ((size_t)(e * CAP + m0 + arow)) * HID + gk;
    bS[i] = w2t + ((size_t)e * DIM + n0 + arow) * HID + gk;
    dOff[i] = chunk * 512;
  }

  f32x4 acc[8][4] = {};
  const int lr = lane & 15, hi4 = lane >> 4;

#define STAGE2(buf, k0) do { \
  _Pragma("unroll") \
  for (int i = 0; i < 4; ++i) { \
    gl16(aS[i] + (k0), &Asm[buf][dOff[i]]); \
    gl16(bS[i] + (k0), &Bsm[buf][dOff[i]]); \
  } } while (0)

  STAGE2(0, 0);
  asm volatile("s_waitcnt vmcnt(0)" ::: "memory");
  __builtin_amdgcn_s_barrier();
#pragma unroll 1
  for (int tt = 0; tt < 15; ++tt) {               // HID/64 - 1
    const int cur = tt & 1;
    STAGE2(cur ^ 1, (tt + 1) * 64);
    gemm256(Asm[cur], Bsm[cur], wm, wn, lr, hi4, acc);
    asm volatile("s_waitcnt vmcnt(0)" ::: "memory");
    __builtin_amdgcn_s_barrier();
  }
  gemm256(Asm[1], Bsm[1], wm, wn, lr, hi4, acc);

  const int lq = lane >> 4, lc = lane & 15;
#pragma unroll
  for (int mi = 0; mi < 8; ++mi) {
#pragma unroll
    for (int j = 0; j < 4; ++j) {
      const int m_l = wm * 128 + mi * 16 + lq * 4 + j;
      const int tok = tok_idx[e * CAP + m0 + m_l];
      const float wgt = expw[e * CAP + m0 + m_l];
#pragma unroll
      for (int ni = 0; ni < 4; ++ni) {
        const int n_l = wn * 64 + ni * 16 + lc;
        float v = (acc[mi][ni][j] + b2[e * DIM + n0 + n_l]) * wgt;
        atomicAdd(out + (size_t)tok * DIM + (n0 + n_l), v);
      }
    }
  }
}

// ===================== fallback f32-input GEMMs (ws too small) =====================
#define SWZ(row, cb) ((cb) ^ (((((row) >> 3) ^ (row)) & 7) << 4))

__global__ __launch_bounds__(256)
void fc1_kernel(const float* __restrict__ x, const int* __restrict__ tok_idx,
                const float* __restrict__ w1, const float* __restrict__ b1,
                u16* __restrict__ h) {
  const int bx = blockIdx.x;
  const int e  = bx >> 5;
  const int mt = (bx >> 3) & 3;
  const int nt = bx & 7;
  const int m0 = mt * 128, n0 = nt * 128;
  const int t = threadIdx.x;
  const int lane = t & 63, wave = t >> 6;
  const int wm = wave >> 1, wn = wave & 1;

  __shared__ __align__(16) u16 Asm[128 * 64];
  __shared__ __align__(16) u16 Bsm[128 * 64];

  const int arq = t & 31, akq = t >> 5;
  int tokr[4];
#pragma unroll
  for (int j = 0; j < 4; ++j) tokr[j] = tok_idx[e * CAP + m0 + arq * 4 + j];
  const int nq = t & 31, kq = t >> 5;
  const float* bptr = w1 + (size_t)e * DIM * HID + n0 + nq * 4;

  f32x4 acc[4][4] = {};

  for (int k0 = 0; k0 < DIM; k0 += 64) {
    float4 av0[4], av1[4];
#pragma unroll
    for (int j = 0; j < 4; ++j) {
      const float* ap = x + (size_t)tokr[j] * DIM + k0 + akq * 8;
      av0[j] = *(const float4*)(ap);
      av1[j] = *(const float4*)(ap + 4);
    }
    float4 bv[8];
#pragma unroll
    for (int kk = 0; kk < 8; ++kk)
      bv[kk] = *(const float4*)(bptr + (size_t)(k0 + kq * 8 + kk) * HID);
    __syncthreads();
#pragma unroll
    for (int j = 0; j < 4; ++j) {
      const int row = arq * 4 + j;
      ushort4 w0, w1v;
      w0.x = f2bf(av0[j].x); w0.y = f2bf(av0[j].y); w0.z = f2bf(av0[j].z); w0.w = f2bf(av0[j].w);
      w1v.x = f2bf(av1[j].x); w1v.y = f2bf(av1[j].y); w1v.z = f2bf(av1[j].z); w1v.w = f2bf(av1[j].w);
      *(ushort4*)((char*)Asm + row * 128 + SWZ(row, (akq * 8 + 0) * 2)) = w0;
      *(ushort4*)((char*)Asm + row * 128 + SWZ(row, (akq * 8 + 4) * 2)) = w1v;
    }
#pragma unroll
    for (int g = 0; g < 2; ++g) {
#pragma unroll
      for (int j = 0; j < 4; ++j) {
        ushort4 wv;
        wv.x = f2bf(GET4(bv[g * 4 + 0], j));
        wv.y = f2bf(GET4(bv[g * 4 + 1], j));
        wv.z = f2bf(GET4(bv[g * 4 + 2], j));
        wv.w = f2bf(GET4(bv[g * 4 + 3], j));
        const int row = nq * 4 + j;
        const int cb = (kq * 8 + g * 4) * 2;
        *(ushort4*)((char*)Bsm + row * 128 + SWZ(row, cb)) = wv;
      }
    }
    __syncthreads();
#pragma unroll
    for (int ks = 0; ks < 2; ++ks) {
      bf16x8 af[4], bf[4];
#pragma unroll
      for (int mi = 0; mi < 4; ++mi) {
        const int row = wm * 64 + mi * 16 + (lane & 15);
        const int cb = ks * 64 + (lane >> 4) * 16;
        af[mi] = *(const bf16x8*)((const char*)Asm + row * 128 + SWZ(row, cb));
      }
#pragma unroll
      for (int ni = 0; ni < 4; ++ni) {
        const int row = wn * 64 + ni * 16 + (lane & 15);
        const int cb = ks * 64 + (lane >> 4) * 16;
        bf[ni] = *(const bf16x8*)((const char*)Bsm + row * 128 + SWZ(row, cb));
      }
#pragma unroll
      for (int mi = 0; mi < 4; ++mi)
#pragma unroll
        for (int ni = 0; ni < 4; ++ni)
          acc[mi][ni] = __builtin_amdgcn_mfma_f32_16x16x32_bf16(af[mi], bf[ni], acc[mi][ni], 0, 0, 0);
    }
  }
  const int lq = lane >> 4, lc = lane & 15;
#pragma unroll
  for (int ni = 0; ni < 4; ++ni) {
    const int n_l = wn * 64 + ni * 16 + lc;
    const float bias = b1[e * HID + n0 + n_l];
#pragma unroll
    for (int mi = 0; mi < 4; ++mi) {
#pragma unroll
      for (int j = 0; j < 4; ++j) {
        const int m_l = wm * 64 + mi * 16 + lq * 4 + j;
        float v = acc[mi][ni][j] + bias;
        float gv = 0.5f * v * (1.0f + erff(v * 0.70710678118654752f));
        h[((size_t)(e * CAP + m0 + m_l)) * HID + (n0 + n_l)] = f2bf(gv);
      }
    }
  }
}

__global__ __launch_bounds__(256)
void fc2_kernel(const u16* __restrict__ h, const float* __restrict__ w2,
                const float* __restrict__ b2, const int* __restrict__ tok_idx,
                const float* __restrict__ expw, float* __restrict__ out) {
  const int bx = blockIdx.x;
  const int e  = bx >> 4;
  const int mt = (bx >> 2) & 3;
  const int nt = bx & 3;
  const int m0 = mt * 128, n0 = nt * 128;
  const int t = threadIdx.x;
  const int lane = t & 63, wave = t >> 6;
  const int wm = wave >> 1, wn = wave & 1;

  __shared__ __align__(16) u16 Asm[128 * 64];
  __shared__ __align__(16) u16 Bsm[128 * 64];

  const int arq = t & 31, akq = t >> 5;
  const u16* aptr0 = h + ((size_t)(e * CAP + m0 + arq * 4)) * HID + akq * 8;
  const int nq = t & 31, kq = t >> 5;
  const float* bptr = w2 + (size_t)e * HID * DIM + n0 + nq * 4;

  f32x4 acc[4][4] = {};

  for (int k0 = 0; k0 < HID; k0 += 64) {
    uint4 av[4];
#pragma unroll
    for (int j = 0; j < 4; ++j)
      av[j] = *(const uint4*)(aptr0 + (size_t)j * HID + k0);
    float4 bv[8];
#pragma unroll
    for (int kk = 0; kk < 8; ++kk)
      bv[kk] = *(const float4*)(bptr + (size_t)(k0 + kq * 8 + kk) * DIM);
    __syncthreads();
#pragma unroll
    for (int j = 0; j < 4; ++j) {
      const int row = arq * 4 + j;
      *(uint4*)((char*)Asm + row * 128 + SWZ(row, akq * 16)) = av[j];
    }
#pragma unroll
    for (int g = 0; g < 2; ++g) {
#pragma unroll
      for (int j = 0; j < 4; ++j) {
        ushort4 wv;
        wv.x = f2bf(GET4(bv[g * 4 + 0], j));
        wv.y = f2bf(GET4(bv[g * 4 + 1], j));
        wv.z = f2bf(GET4(bv[g * 4 + 2], j));
        wv.w = f2bf(GET4(bv[g * 4 + 3], j));
        const int row = nq * 4 + j;
        const int cb = (kq * 8 + g * 4) * 2;
        *(ushort4*)((char*)Bsm + row * 128 + SWZ(row, cb)) = wv;
      }
    }
    __syncthreads();
#pragma unroll
    for (int ks = 0; ks < 2; ++ks) {
      bf16x8 af[4], bf[4];
#pragma unroll
      for (int mi = 0; mi < 4; ++mi) {
        const int row = wm * 64 + mi * 16 + (lane & 15);
        const int cb = ks * 64 + (lane >> 4) * 16;
        af[mi] = *(const bf16x8*)((const char*)Asm + row * 128 + SWZ(row, cb));
      }
#pragma unroll
      for (int ni = 0; ni < 4; ++ni) {
        const int row = wn * 64 + ni * 16 + (lane & 15);
        const int cb = ks * 64 + (lane >> 4) * 16;
        bf[ni] = *(const bf16x8*)((const char*)Bsm + row * 128 + SWZ(row, cb));
      }
#pragma unroll
      for (int mi = 0; mi < 4; ++mi)
#pragma unroll
        for (int ni = 0; ni < 4; ++ni)
          acc[mi][ni] = __builtin_amdgcn_mfma_f32_16x16x32_bf16(af[mi], bf[ni], acc[mi][ni], 0, 0, 0);
    }
  }
  const int lq = lane >> 4, lc = lane & 15;
  int   tokm[4][4];
  float wgt[4][4];
#pragma unroll
  for (int mi = 0; mi < 4; ++mi)
#pragma unroll
    for (int j = 0; j < 4; ++j) {
      const int m_l = wm * 64 + mi * 16 + lq * 4 + j;
      tokm[mi][j] = tok_idx[e * CAP + m0 + m_l];
      wgt[mi][j]  = expw[e * CAP + m0 + m_l];
    }
#pragma unroll
  for (int ni = 0; ni < 4; ++ni) {
    const int n_l = wn * 64 + ni * 16 + lc;
    const float bias = b2[e * DIM + n0 + n_l];
#pragma unroll
    for (int mi = 0; mi < 4; ++mi)
#pragma unroll
      for (int j = 0; j < 4; ++j) {
        float v = (acc[mi][ni][j] + bias) * wgt[mi][j];
        atomicAdd(out + (size_t)tokm[mi][j] * DIM + (n0 + n_l), v);
      }
  }
}

extern "C" void kernel_launch(void* const* d_in, const int* in_sizes, int n_in,
                              void* d_out, int out_size, void* d_ws, size_t ws_size,
                              hipStream_t stream) {
  const float* x  = (const float*)d_in[0];
  const float* rw = (const float*)d_in[1];
  const float* w1 = (const float*)d_in[2];
  const float* b1 = (const float*)d_in[3];
  const float* w2 = (const float*)d_in[4];
  const float* b2 = (const float*)d_in[5];
  float* out = (float*)d_out;

  char* ws = (char*)d_ws;
  const size_t MB = 1u << 20;
  float* logits = (float*)ws;                                   // [0, 8M)
  int*   toki   = (int*)(ws + 8 * MB);                          // 128 KB
  float* ew     = (float*)(ws + 8 * MB + (128u << 10));         // 128 KB

  (void)hipMemsetAsync(d_out, 0, (size_t)out_size * sizeof(float), stream);
  router_kernel<<<dim3(1024), dim3(256), 0, stream>>>(x, rw, logits);
  topk_kernel<<<dim3(64), dim3(1024), 0, stream>>>(logits, toki, ew, out + (size_t)N_TOK * DIM);

  const size_t off_xb = 8 * MB + (256u << 10);   // 8.25M
  const size_t off_wt = off_xb + 32 * MB;        // 40.25M
  const size_t off_h  = off_wt + 64 * MB;        // 104.25M
  const size_t need   = off_h + 64 * MB;         // 168.25M

  if (ws_size >= need) {
    u16* xb  = (u16*)(ws + off_xb);
    u16* wt  = (u16*)(ws + off_wt);
    u16* h   = (u16*)(ws + off_h);
    cvt_bf16_kernel<<<dim3(8192), dim3(256), 0, stream>>>(x, xb);
    transpose_cvt_kernel<<<dim3(16, 8, 64), dim3(256), 0, stream>>>(w1, wt, 512, 1024);
    fc1_bf<<<dim3(512), dim3(512), 0, stream>>>(xb, toki, wt, b1, h);
    transpose_cvt_kernel<<<dim3(8, 16, 64), dim3(256), 0, stream>>>(w2, wt, 1024, 512);
    fc2_bf<<<dim3(256), dim3(512), 0, stream>>>(h, wt, b2, toki, ew, out);
  } else {
    u16* h = (u16*)(ws + 8 * MB + (256u << 10)); // old layout
    fc1_kernel<<<dim3(2048), dim3(256), 0, stream>>>(x, toki, w1, b1, h);
    fc2_kernel<<<dim3(1024), dim3(256), 0, stream>>>(h, w2, b2, toki, ew, out);
  }
}

// Round 10
// 519.118 us; speedup vs baseline: 1.0817x; 1.0802x over previous
//
#include <hip/hip_runtime.h>
#include <math.h>

#define N_TOK 32768
#define DIM   512
#define NEXP  64
#define HID   1024
#define CAP   512

typedef float  f32x4  __attribute__((ext_vector_type(4)));
typedef short  bf16x8 __attribute__((ext_vector_type(8)));
typedef unsigned short u16;

#define GET4(v, jj) ((jj) == 0 ? (v).x : (jj) == 1 ? (v).y : (jj) == 2 ? (v).z : (v).w)

__device__ __forceinline__ u16 f2bf(float f) {
  unsigned u = __float_as_uint(f);
  u += 0x7FFFu + ((u >> 16) & 1u);   // RNE
  return (u16)(u >> 16);
}
__device__ __forceinline__ unsigned enc_f(float f) {  // monotone f32 -> u32
  unsigned u = __float_as_uint(f);
  return (u & 0x80000000u) ? ~u : (u | 0x80000000u);
}
__device__ __forceinline__ float dec_f(unsigned k) {
  unsigned u = (k & 0x80000000u) ? (k & 0x7FFFFFFFu) : ~k;
  return __uint_as_float(u);
}
__device__ __forceinline__ void gl16(const u16* g, u16* l) {
  __builtin_amdgcn_global_load_lds(
      (const __attribute__((address_space(1))) unsigned int*)g,
      (__attribute__((address_space(3))) unsigned int*)l, 16, 0, 0);
}

// ---------------- router ----------------
__global__ __launch_bounds__(256)
void router_kernel(const float* __restrict__ x, const float* __restrict__ rw,
                   float* __restrict__ logitsT) {
  const int t = threadIdx.x;
  const int n0 = blockIdx.x * 32 + (t >> 4) * 2;
  const int e0 = (t & 15) * 4;
  float acc[8];
#pragma unroll
  for (int i = 0; i < 8; ++i) acc[i] = 0.f;
  const float* xr0 = x + (size_t)(n0 + 0) * DIM;
  const float* xr1 = x + (size_t)(n0 + 1) * DIM;
  for (int k0 = 0; k0 < DIM; k0 += 4) {
    float4 a0 = *(const float4*)(xr0 + k0);
    float4 a1 = *(const float4*)(xr1 + k0);
#pragma unroll
    for (int kk = 0; kk < 4; ++kk) {
      float4 b = *(const float4*)(rw + (size_t)(k0 + kk) * NEXP + e0);
      float d0 = GET4(a0, kk);
      float d1 = GET4(a1, kk);
      acc[0] += d0 * b.x; acc[1] += d0 * b.y; acc[2] += d0 * b.z; acc[3] += d0 * b.w;
      acc[4] += d1 * b.x; acc[5] += d1 * b.y; acc[6] += d1 * b.z; acc[7] += d1 * b.w;
    }
  }
#pragma unroll
  for (int j = 0; j < 2; ++j)
#pragma unroll
    for (int ee = 0; ee < 4; ++ee)
      logitsT[(size_t)(e0 + ee) * N_TOK + (n0 + j)] = acc[j * 4 + ee];
}

// ------------- topk -------------
__global__ __launch_bounds__(1024)
void topk_kernel(const float* __restrict__ logitsT, int* __restrict__ tok_idx,
                 float* __restrict__ expw, float* __restrict__ auxout) {
  const int e = blockIdx.x;
  const int t = threadIdx.x;
  const float* row = logitsT + (size_t)e * N_TOK;

  unsigned key[32];          // token n = j*1024 + t
#pragma unroll
  for (int j = 0; j < 32; ++j) key[j] = enc_f(row[j * 1024 + t]);

  __shared__ unsigned ured[1024];
  __shared__ float    fred[1024];
  __shared__ unsigned hist[256];
  __shared__ unsigned sh_chosen, sh_rem, sh_x, sh_pos;

  unsigned km = 0;
#pragma unroll
  for (int j = 0; j < 32; ++j) km = key[j] > km ? key[j] : km;
  ured[t] = km;
  __syncthreads();
  for (int s = 512; s > 0; s >>= 1) {
    if (t < s) { unsigned o = ured[t + s]; if (o > ured[t]) ured[t] = o; }
    __syncthreads();
  }
  const float m = dec_f(ured[0]);

  float ssum = 0.f;
#pragma unroll
  for (int j = 0; j < 32; ++j) ssum += expf(dec_f(key[j]) - m);
  fred[t] = ssum;
  __syncthreads();
  for (int s = 512; s > 0; s >>= 1) {
    if (t < s) fred[t] += fred[t + s];
    __syncthreads();
  }
  const float invZ = 1.0f / fred[0];

  if (t == 0) sh_rem = CAP;
  __syncthreads();
  unsigned live = 0xFFFFFFFFu;
  unsigned prefix = 0;
  for (int pass = 0; pass < 4; ++pass) {
    const int shift = 24 - pass * 8;
    if (t < 256) hist[t] = 0;
    __syncthreads();
#pragma unroll
    for (int j = 0; j < 32; ++j)
      if (live & (1u << j)) atomicAdd(&hist[(key[j] >> shift) & 0xFFu], 1u);
    __syncthreads();
    if (t == 0) {
      unsigned need = sh_rem, accum = 0;
      int found = 0;
      for (int b = 255; b >= 0; --b) {
        unsigned cn = hist[b];
        if (!found) {
          if (accum + cn >= need) { sh_chosen = (unsigned)b; sh_rem = need - accum; found = 1; }
          else accum += cn;
        }
      }
    }
    __syncthreads();
    const unsigned ch = sh_chosen;
#pragma unroll
    for (int j = 0; j < 32; ++j)
      if (((key[j] >> shift) & 0xFFu) != ch) live &= ~(1u << j);
    prefix = (prefix << 8) | ch;
    __syncthreads();
  }
  const unsigned ustar = prefix;

  if (t == 0) sh_pos = 0;
  __syncthreads();
#pragma unroll
  for (int j = 0; j < 32; ++j) {
    if (key[j] > ustar) {
      unsigned p = atomicAdd(&sh_pos, 1u);
      tok_idx[e * CAP + p] = j * 1024 + t;
      expw[e * CAP + p] = expf(dec_f(key[j]) - m) * invZ;
    }
  }
  __syncthreads();
  const unsigned padv = CAP - sh_pos;

  if (t < 256) hist[t] = 0;
  __syncthreads();
#pragma unroll
  for (int j = 0; j < 32; ++j)
    if (live & (1u << j)) atomicAdd(&hist[(j * 1024 + t) >> 7], 1u);
  __syncthreads();
  if (t == 0) {
    unsigned accum = 0;
    int found = 0;
    for (int b = 0; b < 256; ++b) {
      unsigned cn = hist[b];
      if (!found) {
        if (accum + cn >= padv) { sh_chosen = (unsigned)b; sh_rem = padv - accum; found = 1; }
        else accum += cn;
      }
    }
  }
  __syncthreads();
  const unsigned hb = sh_chosen, rem = sh_rem;
  if (t < 256) hist[t] = 0;
  __syncthreads();
#pragma unroll
  for (int j = 0; j < 32; ++j)
    if (live & (1u << j)) {
      int n = j * 1024 + t;
      if ((unsigned)(n >> 7) == hb) atomicAdd(&hist[n & 127], 1u);
    }
  __syncthreads();
  if (t == 0) {
    unsigned accum = 0;
    int found = 0;
    for (int b = 0; b < 128; ++b) {
      unsigned cn = hist[b];
      if (!found) {
        if (accum + cn >= rem) { sh_x = (hb << 7) | (unsigned)b; found = 1; }
        else accum += cn;
      }
    }
  }
  __syncthreads();
  const int X = (int)sh_x;
#pragma unroll
  for (int j = 0; j < 32; ++j)
    if (live & (1u << j)) {
      int n = j * 1024 + t;
      if (n <= X) {
        unsigned p = atomicAdd(&sh_pos, 1u);
        tok_idx[e * CAP + p] = n;
        expw[e * CAP + p] = expf(dec_f(key[j]) - m) * invZ;
      }
    }
  if (e == 0 && t == 0) { auxout[0] = 2.44140625e-4f; auxout[1] = 0.015625f; }
}

// ---------------- prep: f32 -> bf16 cast ----------------
__global__ __launch_bounds__(256)
void cvt_bf16_kernel(const float* __restrict__ in, u16* __restrict__ outp) {
  size_t i = ((size_t)blockIdx.x * 256 + threadIdx.x) * 8;
  float4 v0 = *(const float4*)(in + i);
  float4 v1 = *(const float4*)(in + i + 4);
  uint4 o;
  o.x = f2bf(v0.x) | ((unsigned)f2bf(v0.y) << 16);
  o.y = f2bf(v0.z) | ((unsigned)f2bf(v0.w) << 16);
  o.z = f2bf(v1.x) | ((unsigned)f2bf(v1.y) << 16);
  o.w = f2bf(v1.z) | ((unsigned)f2bf(v1.w) << 16);
  *(uint4*)(outp + i) = o;
}

// ---------------- prep: per-expert transpose+cvt: f32 [E][R][C] -> bf16 [E][C][R] ----------------
__global__ __launch_bounds__(256)
void transpose_cvt_kernel(const float* __restrict__ in, u16* __restrict__ outp,
                          int R, int C) {
  __shared__ u16 tile[64][66];
  const int e = blockIdx.z;
  const int r0 = blockIdx.y * 64, c0 = blockIdx.x * 64;
  const int t = threadIdx.x;
  {
    const int r = t >> 2, cs = (t & 3) * 16;
    const float* ip = in + ((size_t)e * R + (r0 + r)) * C + c0 + cs;
#pragma unroll
    for (int q = 0; q < 4; ++q) {
      float4 v = *(const float4*)(ip + q * 4);
      tile[r][cs + q * 4 + 0] = f2bf(v.x);
      tile[r][cs + q * 4 + 1] = f2bf(v.y);
      tile[r][cs + q * 4 + 2] = f2bf(v.z);
      tile[r][cs + q * 4 + 3] = f2bf(v.w);
    }
  }
  __syncthreads();
  {
    const int c = t >> 2, rs = (t & 3) * 16;
    u16* op = outp + ((size_t)e * C + (c0 + c)) * R + r0 + rs;
    uint4 o0, o1;
    o0.x = tile[rs + 0][c]  | ((unsigned)tile[rs + 1][c]  << 16);
    o0.y = tile[rs + 2][c]  | ((unsigned)tile[rs + 3][c]  << 16);
    o0.z = tile[rs + 4][c]  | ((unsigned)tile[rs + 5][c]  << 16);
    o0.w = tile[rs + 6][c]  | ((unsigned)tile[rs + 7][c]  << 16);
    o1.x = tile[rs + 8][c]  | ((unsigned)tile[rs + 9][c]  << 16);
    o1.y = tile[rs + 10][c] | ((unsigned)tile[rs + 11][c] << 16);
    o1.z = tile[rs + 12][c] | ((unsigned)tile[rs + 13][c] << 16);
    o1.w = tile[rs + 14][c] | ((unsigned)tile[rs + 15][c] << 16);
    *(uint4*)(op) = o0;
    *(uint4*)(op + 8) = o1;
  }
}

// ===================== bf16 GEMMs: 128x128 dbuf, counted-vmcnt pipeline =====================
__device__ __forceinline__ void gemm_step(const u16* As, const u16* Bs,
                                          int wm, int wn, int lr, int hi4,
                                          f32x4 acc[4][4]) {
#pragma unroll
  for (int ks = 0; ks < 2; ++ks) {
    bf16x8 af[4], bf[4];
#pragma unroll
    for (int mi = 0; mi < 4; ++mi) {
      const int row = wm * 64 + mi * 16 + lr;
      const int kb = ks * 64 + hi4 * 16;
      af[mi] = *(const bf16x8*)((const char*)As + row * 128 + (kb ^ ((row & 7) << 4)));
    }
#pragma unroll
    for (int ni = 0; ni < 4; ++ni) {
      const int row = wn * 64 + ni * 16 + lr;
      const int kb = ks * 64 + hi4 * 16;
      bf[ni] = *(const bf16x8*)((const char*)Bs + row * 128 + (kb ^ ((row & 7) << 4)));
    }
#pragma unroll
    for (int mi = 0; mi < 4; ++mi)
#pragma unroll
      for (int ni = 0; ni < 4; ++ni)
        acc[mi][ni] = __builtin_amdgcn_mfma_f32_16x16x32_bf16(af[mi], bf[ni], acc[mi][ni], 0, 0, 0);
  }
}

__global__ __launch_bounds__(256)
void fc1_bf(const u16* __restrict__ xb, const int* __restrict__ tok_idx,
            const u16* __restrict__ w1t, const float* __restrict__ b1,
            u16* __restrict__ h) {
  const int bx0 = blockIdx.x;
  const int bx = (bx0 & 7) * 256 + (bx0 >> 3);   // bijective XCD remap (2048 = 8*256)
  const int e  = bx >> 5;
  const int mt = (bx >> 3) & 3;
  const int nt = bx & 7;
  const int m0 = mt * 128, n0 = nt * 128;
  const int t = threadIdx.x;
  const int lane = t & 63, wave = t >> 6;
  const int wm = wave >> 1, wn = wave & 1;

  __shared__ __align__(16) u16 Asm[2][128 * 64];  // 32 KB
  __shared__ __align__(16) u16 Bsm[2][128 * 64];  // 32 KB

  const int gk = ((lane & 7) ^ (lane >> 3)) * 8;  // inverse-swizzled k elem offset
  const int rsub = lane >> 3;

  const u16* aS[4]; const u16* bS[4];
  int dOff[4];
#pragma unroll
  for (int i = 0; i < 4; ++i) {
    const int chunk = wave * 4 + i;
    const int arow = chunk * 8 + rsub;             // 0..127
    const int tok = tok_idx[e * CAP + m0 + arow];
    aS[i] = xb + (size_t)tok * DIM + gk;
    bS[i] = w1t + ((size_t)e * HID + n0 + arow) * DIM + gk;
    dOff[i] = chunk * 512;
  }

  f32x4 acc[4][4] = {};
  const int lr = lane & 15, hi4 = lane >> 4;

#define STAGE_F1(buf, k0) do { \
  _Pragma("unroll") \
  for (int i = 0; i < 4; ++i) { \
    gl16(aS[i] + (k0), &Asm[buf][dOff[i]]); \
    gl16(bS[i] + (k0), &Bsm[buf][dOff[i]]); \
  } } while (0)

  STAGE_F1(0, 0);
#pragma unroll
  for (int tt = 0; tt < 7; ++tt) {               // DIM/64 - 1 = 7
    const int cur = tt & 1;
    STAGE_F1(cur ^ 1, (tt + 1) * 64);            // prefetch next (8 loads in flight)
    asm volatile("s_waitcnt vmcnt(8)" ::: "memory");  // wait ONLY stage(tt)
    __builtin_amdgcn_s_barrier();                // all waves staged tt
    gemm_step(Asm[cur], Bsm[cur], wm, wn, lr, hi4, acc);
    __builtin_amdgcn_s_barrier();                // WAR: buffer reuse next iter
  }
  asm volatile("s_waitcnt vmcnt(0)" ::: "memory");
  __builtin_amdgcn_s_barrier();
  gemm_step(Asm[1], Bsm[1], wm, wn, lr, hi4, acc);

  const int lq = lane >> 4, lc = lane & 15;
#pragma unroll
  for (int ni = 0; ni < 4; ++ni) {
    const int n_l = wn * 64 + ni * 16 + lc;
    const float bias = b1[e * HID + n0 + n_l];
#pragma unroll
    for (int mi = 0; mi < 4; ++mi) {
#pragma unroll
      for (int j = 0; j < 4; ++j) {
        const int m_l = wm * 64 + mi * 16 + lq * 4 + j;
        float v = acc[mi][ni][j] + bias;
        float gv = 0.5f * v * (1.0f + erff(v * 0.70710678118654752f));
        h[((size_t)(e * CAP + m0 + m_l)) * HID + (n0 + n_l)] = f2bf(gv);
      }
    }
  }
}

__global__ __launch_bounds__(256)
void fc2_bf(const u16* __restrict__ h, const u16* __restrict__ w2t,
            const float* __restrict__ b2, const int* __restrict__ tok_idx,
            const float* __restrict__ expw, float* __restrict__ out) {
  const int bx0 = blockIdx.x;
  const int bx = (bx0 & 7) * 128 + (bx0 >> 3);   // bijective XCD remap (1024 = 8*128)
  const int e  = bx >> 4;
  const int mt = (bx >> 2) & 3;
  const int nt = bx & 3;
  const int m0 = mt * 128, n0 = nt * 128;
  const int t = threadIdx.x;
  const int lane = t & 63, wave = t >> 6;
  const int wm = wave >> 1, wn = wave & 1;

  __shared__ __align__(16) u16 Asm[2][128 * 64];
  __shared__ __align__(16) u16 Bsm[2][128 * 64];

  const int gk = ((lane & 7) ^ (lane >> 3)) * 8;
  const int rsub = lane >> 3;

  const u16* aS[4]; const u16* bS[4];
  int dOff[4];
#pragma unroll
  for (int i = 0; i < 4; ++i) {
    const int chunk = wave * 4 + i;
    const int arow = chunk * 8 + rsub;
    aS[i] = h + ((size_t)(e * CAP + m0 + arow)) * HID + gk;
    bS[i] = w2t + ((size_t)e * DIM + n0 + arow) * HID + gk;
    dOff[i] = chunk * 512;
  }

  f32x4 acc[4][4] = {};
  const int lr = lane & 15, hi4 = lane >> 4;

#define STAGE_F2(buf, k0) do { \
  _Pragma("unroll") \
  for (int i = 0; i < 4; ++i) { \
    gl16(aS[i] + (k0), &Asm[buf][dOff[i]]); \
    gl16(bS[i] + (k0), &Bsm[buf][dOff[i]]); \
  } } while (0)

  STAGE_F2(0, 0);
#pragma unroll 3
  for (int tt = 0; tt < 15; ++tt) {              // HID/64 - 1 = 15
    const int cur = tt & 1;
    STAGE_F2(cur ^ 1, (tt + 1) * 64);
    asm volatile("s_waitcnt vmcnt(8)" ::: "memory");
    __builtin_amdgcn_s_barrier();
    gemm_step(Asm[cur], Bsm[cur], wm, wn, lr, hi4, acc);
    __builtin_amdgcn_s_barrier();
  }
  asm volatile("s_waitcnt vmcnt(0)" ::: "memory");
  __builtin_amdgcn_s_barrier();
  gemm_step(Asm[1], Bsm[1], wm, wn, lr, hi4, acc);

  const int lq = lane >> 4, lc = lane & 15;
  int   tokm[4][4];
  float wgt[4][4];
#pragma unroll
  for (int mi = 0; mi < 4; ++mi)
#pragma unroll
    for (int j = 0; j < 4; ++j) {
      const int m_l = wm * 64 + mi * 16 + lq * 4 + j;
      tokm[mi][j] = tok_idx[e * CAP + m0 + m_l];
      wgt[mi][j]  = expw[e * CAP + m0 + m_l];
    }
#pragma unroll
  for (int ni = 0; ni < 4; ++ni) {
    const int n_l = wn * 64 + ni * 16 + lc;
    const float bias = b2[e * DIM + n0 + n_l];
#pragma unroll
    for (int mi = 0; mi < 4; ++mi)
#pragma unroll
      for (int j = 0; j < 4; ++j) {
        float v = (acc[mi][ni][j] + bias) * wgt[mi][j];
        atomicAdd(out + (size_t)tokm[mi][j] * DIM + (n0 + n_l), v);
      }
  }
}

// ===================== fallback f32-input GEMMs (ws too small) =====================
#define SWZ(row, cb) ((cb) ^ (((((row) >> 3) ^ (row)) & 7) << 4))

__global__ __launch_bounds__(256)
void fc1_kernel(const float* __restrict__ x, const int* __restrict__ tok_idx,
                const float* __restrict__ w1, const float* __restrict__ b1,
                u16* __restrict__ h) {
  const int bx = blockIdx.x;
  const int e  = bx >> 5;
  const int mt = (bx >> 3) & 3;
  const int nt = bx & 7;
  const int m0 = mt * 128, n0 = nt * 128;
  const int t = threadIdx.x;
  const int lane = t & 63, wave = t >> 6;
  const int wm = wave >> 1, wn = wave & 1;

  __shared__ __align__(16) u16 Asm[128 * 64];
  __shared__ __align__(16) u16 Bsm[128 * 64];

  const int arq = t & 31, akq = t >> 5;
  int tokr[4];
#pragma unroll
  for (int j = 0; j < 4; ++j) tokr[j] = tok_idx[e * CAP + m0 + arq * 4 + j];
  const int nq = t & 31, kq = t >> 5;
  const float* bptr = w1 + (size_t)e * DIM * HID + n0 + nq * 4;

  f32x4 acc[4][4] = {};

  for (int k0 = 0; k0 < DIM; k0 += 64) {
    float4 av0[4], av1[4];
#pragma unroll
    for (int j = 0; j < 4; ++j) {
      const float* ap = x + (size_t)tokr[j] * DIM + k0 + akq * 8;
      av0[j] = *(const float4*)(ap);
      av1[j] = *(const float4*)(ap + 4);
    }
    float4 bv[8];
#pragma unroll
    for (int kk = 0; kk < 8; ++kk)
      bv[kk] = *(const float4*)(bptr + (size_t)(k0 + kq * 8 + kk) * HID);
    __syncthreads();
#pragma unroll
    for (int j = 0; j < 4; ++j) {
      const int row = arq * 4 + j;
      ushort4 w0, w1v;
      w0.x = f2bf(av0[j].x); w0.y = f2bf(av0[j].y); w0.z = f2bf(av0[j].z); w0.w = f2bf(av0[j].w);
      w1v.x = f2bf(av1[j].x); w1v.y = f2bf(av1[j].y); w1v.z = f2bf(av1[j].z); w1v.w = f2bf(av1[j].w);
      *(ushort4*)((char*)Asm + row * 128 + SWZ(row, (akq * 8 + 0) * 2)) = w0;
      *(ushort4*)((char*)Asm + row * 128 + SWZ(row, (akq * 8 + 4) * 2)) = w1v;
    }
#pragma unroll
    for (int g = 0; g < 2; ++g) {
#pragma unroll
      for (int j = 0; j < 4; ++j) {
        ushort4 wv;
        wv.x = f2bf(GET4(bv[g * 4 + 0], j));
        wv.y = f2bf(GET4(bv[g * 4 + 1], j));
        wv.z = f2bf(GET4(bv[g * 4 + 2], j));
        wv.w = f2bf(GET4(bv[g * 4 + 3], j));
        const int row = nq * 4 + j;
        const int cb = (kq * 8 + g * 4) * 2;
        *(ushort4*)((char*)Bsm + row * 128 + SWZ(row, cb)) = wv;
      }
    }
    __syncthreads();
#pragma unroll
    for (int ks = 0; ks < 2; ++ks) {
      bf16x8 af[4], bf[4];
#pragma unroll
      for (int mi = 0; mi < 4; ++mi) {
        const int row = wm * 64 + mi * 16 + (lane & 15);
        const int cb = ks * 64 + (lane >> 4) * 16;
        af[mi] = *(const bf16x8*)((const char*)Asm + row * 128 + SWZ(row, cb));
      }
#pragma unroll
      for (int ni = 0; ni < 4; ++ni) {
        const int row = wn * 64 + ni * 16 + (lane & 15);
        const int cb = ks * 64 + (lane >> 4) * 16;
        bf[ni] = *(const bf16x8*)((const char*)Bsm + row * 128 + SWZ(row, cb));
      }
#pragma unroll
      for (int mi = 0; mi < 4; ++mi)
#pragma unroll
        for (int ni = 0; ni < 4; ++ni)
          acc[mi][ni] = __builtin_amdgcn_mfma_f32_16x16x32_bf16(af[mi], bf[ni], acc[mi][ni], 0, 0, 0);
    }
  }
  const int lq = lane >> 4, lc = lane & 15;
#pragma unroll
  for (int ni = 0; ni < 4; ++ni) {
    const int n_l = wn * 64 + ni * 16 + lc;
    const float bias = b1[e * HID + n0 + n_l];
#pragma unroll
    for (int mi = 0; mi < 4; ++mi) {
#pragma unroll
      for (int j = 0; j < 4; ++j) {
        const int m_l = wm * 64 + mi * 16 + lq * 4 + j;
        float v = acc[mi][ni][j] + bias;
        float gv = 0.5f * v * (1.0f + erff(v * 0.70710678118654752f));
        h[((size_t)(e * CAP + m0 + m_l)) * HID + (n0 + n_l)] = f2bf(gv);
      }
    }
  }
}

__global__ __launch_bounds__(256)
void fc2_kernel(const u16* __restrict__ h, const float* __restrict__ w2,
                const float* __restrict__ b2, const int* __restrict__ tok_idx,
                const float* __restrict__ expw, float* __restrict__ out) {
  const int bx = blockIdx.x;
  const int e  = bx >> 4;
  const int mt = (bx >> 2) & 3;
  const int nt = bx & 3;
  const int m0 = mt * 128, n0 = nt * 128;
  const int t = threadIdx.x;
  const int lane = t & 63, wave = t >> 6;
  const int wm = wave >> 1, wn = wave & 1;

  __shared__ __align__(16) u16 Asm[128 * 64];
  __shared__ __align__(16) u16 Bsm[128 * 64];

  const int arq = t & 31, akq = t >> 5;
  const u16* aptr0 = h + ((size_t)(e * CAP + m0 + arq * 4)) * HID + akq * 8;
  const int nq = t & 31, kq = t >> 5;
  const float* bptr = w2 + (size_t)e * HID * DIM + n0 + nq * 4;

  f32x4 acc[4][4] = {};

  for (int k0 = 0; k0 < HID; k0 += 64) {
    uint4 av[4];
#pragma unroll
    for (int j = 0; j < 4; ++j)
      av[j] = *(const uint4*)(aptr0 + (size_t)j * HID + k0);
    float4 bv[8];
#pragma unroll
    for (int kk = 0; kk < 8; ++kk)
      bv[kk] = *(const float4*)(bptr + (size_t)(k0 + kq * 8 + kk) * DIM);
    __syncthreads();
#pragma unroll
    for (int j = 0; j < 4; ++j) {
      const int row = arq * 4 + j;
      *(uint4*)((char*)Asm + row * 128 + SWZ(row, akq * 16)) = av[j];
    }
#pragma unroll
    for (int g = 0; g < 2; ++g) {
#pragma unroll
      for (int j = 0; j < 4; ++j) {
        ushort4 wv;
        wv.x = f2bf(GET4(bv[g * 4 + 0], j));
        wv.y = f2bf(GET4(bv[g * 4 + 1], j));
        wv.z = f2bf(GET4(bv[g * 4 + 2], j));
        wv.w = f2bf(GET4(bv[g * 4 + 3], j));
        const int row = nq * 4 + j;
        const int cb = (kq * 8 + g * 4) * 2;
        *(ushort4*)((char*)Bsm + row * 128 + SWZ(row, cb)) = wv;
      }
    }
    __syncthreads();
#pragma unroll
    for (int ks = 0; ks < 2; ++ks) {
      bf16x8 af[4], bf[4];
#pragma unroll
      for (int mi = 0; mi < 4; ++mi) {
        const int row = wm * 64 + mi * 16 + (lane & 15);
        const int cb = ks * 64 + (lane >> 4) * 16;
        af[mi] = *(const bf16x8*)((const char*)Asm + row * 128 + SWZ(row, cb));
      }
#pragma unroll
      for (int ni = 0; ni < 4; ++ni) {
        const int row = wn * 64 + ni * 16 + (lane & 15);
        const int cb = ks * 64 + (lane >> 4) * 16;
        bf[ni] = *(const bf16x8*)((const char*)Bsm + row * 128 + SWZ(row, cb));
      }
#pragma unroll
      for (int mi = 0; mi < 4; ++mi)
#pragma unroll
        for (int ni = 0; ni < 4; ++ni)
          acc[mi][ni] = __builtin_amdgcn_mfma_f32_16x16x32_bf16(af[mi], bf[ni], acc[mi][ni], 0, 0, 0);
    }
  }
  const int lq = lane >> 4, lc = lane & 15;
  int   tokm[4][4];
  float wgt[4][4];
#pragma unroll
  for (int mi = 0; mi < 4; ++mi)
#pragma unroll
    for (int j = 0; j < 4; ++j) {
      const int m_l = wm * 64 + mi * 16 + lq * 4 + j;
      tokm[mi][j] = tok_idx[e * CAP + m0 + m_l];
      wgt[mi][j]  = expw[e * CAP + m0 + m_l];
    }
#pragma unroll
  for (int ni = 0; ni < 4; ++ni) {
    const int n_l = wn * 64 + ni * 16 + lc;
    const float bias = b2[e * DIM + n0 + n_l];
#pragma unroll
    for (int mi = 0; mi < 4; ++mi)
#pragma unroll
      for (int j = 0; j < 4; ++j) {
        float v = (acc[mi][ni][j] + bias) * wgt[mi][j];
        atomicAdd(out + (size_t)tokm[mi][j] * DIM + (n0 + n_l), v);
      }
  }
}

extern "C" void kernel_launch(void* const* d_in, const int* in_sizes, int n_in,
                              void* d_out, int out_size, void* d_ws, size_t ws_size,
                              hipStream_t stream) {
  const float* x  = (const float*)d_in[0];
  const float* rw = (const float*)d_in[1];
  const float* w1 = (const float*)d_in[2];
  const float* b1 = (const float*)d_in[3];
  const float* w2 = (const float*)d_in[4];
  const float* b2 = (const float*)d_in[5];
  float* out = (float*)d_out;

  char* ws = (char*)d_ws;
  const size_t MB = 1u << 20;
  float* logits = (float*)ws;                                   // [0, 8M)
  int*   toki   = (int*)(ws + 8 * MB);                          // 128 KB
  float* ew     = (float*)(ws + 8 * MB + (128u << 10));         // 128 KB

  (void)hipMemsetAsync(d_out, 0, (size_t)out_size * sizeof(float), stream);
  router_kernel<<<dim3(1024), dim3(256), 0, stream>>>(x, rw, logits);
  topk_kernel<<<dim3(64), dim3(1024), 0, stream>>>(logits, toki, ew, out + (size_t)N_TOK * DIM);

  const size_t off_xb = 8 * MB + (256u << 10);   // 8.25M
  const size_t off_wt = off_xb + 32 * MB;        // 40.25M
  const size_t off_h  = off_wt + 64 * MB;        // 104.25M
  const size_t need   = off_h + 64 * MB;         // 168.25M

  if (ws_size >= need) {
    u16* xb  = (u16*)(ws + off_xb);
    u16* wt  = (u16*)(ws + off_wt);
    u16* h   = (u16*)(ws + off_h);
    cvt_bf16_kernel<<<dim3(8192), dim3(256), 0, stream>>>(x, xb);
    transpose_cvt_kernel<<<dim3(16, 8, 64), dim3(256), 0, stream>>>(w1, wt, 512, 1024);
    fc1_bf<<<dim3(2048), dim3(256), 0, stream>>>(xb, toki, wt, b1, h);
    transpose_cvt_kernel<<<dim3(8, 16, 64), dim3(256), 0, stream>>>(w2, wt, 1024, 512);
    fc2_bf<<<dim3(1024), dim3(256), 0, stream>>>(h, wt, b2, toki, ew, out);
  } else {
    u16* h = (u16*)(ws + 8 * MB + (256u << 10)); // old layout
    fc1_kernel<<<dim3(2048), dim3(256), 0, stream>>>(x, toki, w1, b1, h);
    fc2_kernel<<<dim3(1024), dim3(256), 0, stream>>>(h, w2, b2, toki, ew, out);
  }
}

// Round 11
// 500.933 us; speedup vs baseline: 1.1210x; 1.0363x over previous
//
#include <hip/hip_runtime.h>
#include <math.h>

#define N_TOK 32768
#define DIM   512
#define NEXP  64
#define HID   1024
#define CAP   512

typedef float  f32x4  __attribute__((ext_vector_type(4)));
typedef short  bf16x8 __attribute__((ext_vector_type(8)));
typedef unsigned short u16;

#define GET4(v, jj) ((jj) == 0 ? (v).x : (jj) == 1 ? (v).y : (jj) == 2 ? (v).z : (v).w)

__device__ __forceinline__ u16 f2bf(float f) {
  unsigned u = __float_as_uint(f);
  u += 0x7FFFu + ((u >> 16) & 1u);   // RNE
  return (u16)(u >> 16);
}
__device__ __forceinline__ unsigned enc_f(float f) {  // monotone f32 -> u32
  unsigned u = __float_as_uint(f);
  return (u & 0x80000000u) ? ~u : (u | 0x80000000u);
}
__device__ __forceinline__ float dec_f(unsigned k) {
  unsigned u = (k & 0x80000000u) ? (k & 0x7FFFFFFFu) : ~k;
  return __uint_as_float(u);
}
__device__ __forceinline__ void gl16(const u16* g, u16* l) {
  __builtin_amdgcn_global_load_lds(
      (const __attribute__((address_space(1))) unsigned int*)g,
      (__attribute__((address_space(3))) unsigned int*)l, 16, 0, 0);
}
// exact-enough erf (A&S 7.1.26, |eps|<=1.5e-7) -> gelu
__device__ __forceinline__ float gelu_f(float v) {
  float x = fabsf(v) * 0.70710678118654752f;
  float tt = 1.0f / (1.0f + 0.3275911f * x);
  float poly = tt * (0.254829592f + tt * (-0.284496736f + tt * (1.421413741f +
               tt * (-1.453152027f + tt * 1.061405429f))));
  float erfabs = 1.0f - poly * __expf(-x * x);
  float erfv = v >= 0.f ? erfabs : -erfabs;
  return 0.5f * v * (1.0f + erfv);
}

// ---------------- router ----------------
__global__ __launch_bounds__(256)
void router_kernel(const float* __restrict__ x, const float* __restrict__ rw,
                   float* __restrict__ logitsT) {
  const int t = threadIdx.x;
  const int n0 = blockIdx.x * 32 + (t >> 4) * 2;
  const int e0 = (t & 15) * 4;
  float acc[8];
#pragma unroll
  for (int i = 0; i < 8; ++i) acc[i] = 0.f;
  const float* xr0 = x + (size_t)(n0 + 0) * DIM;
  const float* xr1 = x + (size_t)(n0 + 1) * DIM;
  for (int k0 = 0; k0 < DIM; k0 += 4) {
    float4 a0 = *(const float4*)(xr0 + k0);
    float4 a1 = *(const float4*)(xr1 + k0);
#pragma unroll
    for (int kk = 0; kk < 4; ++kk) {
      float4 b = *(const float4*)(rw + (size_t)(k0 + kk) * NEXP + e0);
      float d0 = GET4(a0, kk);
      float d1 = GET4(a1, kk);
      acc[0] += d0 * b.x; acc[1] += d0 * b.y; acc[2] += d0 * b.z; acc[3] += d0 * b.w;
      acc[4] += d1 * b.x; acc[5] += d1 * b.y; acc[6] += d1 * b.z; acc[7] += d1 * b.w;
    }
  }
#pragma unroll
  for (int j = 0; j < 2; ++j)
#pragma unroll
    for (int ee = 0; ee < 4; ++ee)
      logitsT[(size_t)(e0 + ee) * N_TOK + (n0 + j)] = acc[j * 4 + ee];
}

// ------------- topk -------------
__global__ __launch_bounds__(1024)
void topk_kernel(const float* __restrict__ logitsT, int* __restrict__ tok_idx,
                 float* __restrict__ expw, float* __restrict__ auxout) {
  const int e = blockIdx.x;
  const int t = threadIdx.x;
  const float* row = logitsT + (size_t)e * N_TOK;

  unsigned key[32];          // token n = j*1024 + t
#pragma unroll
  for (int j = 0; j < 32; ++j) key[j] = enc_f(row[j * 1024 + t]);

  __shared__ unsigned ured[1024];
  __shared__ float    fred[1024];
  __shared__ unsigned hist[256];
  __shared__ unsigned sh_chosen, sh_rem, sh_x, sh_pos;

  unsigned km = 0;
#pragma unroll
  for (int j = 0; j < 32; ++j) km = key[j] > km ? key[j] : km;
  ured[t] = km;
  __syncthreads();
  for (int s = 512; s > 0; s >>= 1) {
    if (t < s) { unsigned o = ured[t + s]; if (o > ured[t]) ured[t] = o; }
    __syncthreads();
  }
  const float m = dec_f(ured[0]);

  float ssum = 0.f;
#pragma unroll
  for (int j = 0; j < 32; ++j) ssum += expf(dec_f(key[j]) - m);
  fred[t] = ssum;
  __syncthreads();
  for (int s = 512; s > 0; s >>= 1) {
    if (t < s) fred[t] += fred[t + s];
    __syncthreads();
  }
  const float invZ = 1.0f / fred[0];

  if (t == 0) sh_rem = CAP;
  __syncthreads();
  unsigned live = 0xFFFFFFFFu;
  unsigned prefix = 0;
  for (int pass = 0; pass < 4; ++pass) {
    const int shift = 24 - pass * 8;
    if (t < 256) hist[t] = 0;
    __syncthreads();
#pragma unroll
    for (int j = 0; j < 32; ++j)
      if (live & (1u << j)) atomicAdd(&hist[(key[j] >> shift) & 0xFFu], 1u);
    __syncthreads();
    if (t == 0) {
      unsigned need = sh_rem, accum = 0;
      int found = 0;
      for (int b = 255; b >= 0; --b) {
        unsigned cn = hist[b];
        if (!found) {
          if (accum + cn >= need) { sh_chosen = (unsigned)b; sh_rem = need - accum; found = 1; }
          else accum += cn;
        }
      }
    }
    __syncthreads();
    const unsigned ch = sh_chosen;
#pragma unroll
    for (int j = 0; j < 32; ++j)
      if (((key[j] >> shift) & 0xFFu) != ch) live &= ~(1u << j);
    prefix = (prefix << 8) | ch;
    __syncthreads();
  }
  const unsigned ustar = prefix;

  if (t == 0) sh_pos = 0;
  __syncthreads();
#pragma unroll
  for (int j = 0; j < 32; ++j) {
    if (key[j] > ustar) {
      unsigned p = atomicAdd(&sh_pos, 1u);
      tok_idx[e * CAP + p] = j * 1024 + t;
      expw[e * CAP + p] = expf(dec_f(key[j]) - m) * invZ;
    }
  }
  __syncthreads();
  const unsigned padv = CAP - sh_pos;

  if (t < 256) hist[t] = 0;
  __syncthreads();
#pragma unroll
  for (int j = 0; j < 32; ++j)
    if (live & (1u << j)) atomicAdd(&hist[(j * 1024 + t) >> 7], 1u);
  __syncthreads();
  if (t == 0) {
    unsigned accum = 0;
    int found = 0;
    for (int b = 0; b < 256; ++b) {
      unsigned cn = hist[b];
      if (!found) {
        if (accum + cn >= padv) { sh_chosen = (unsigned)b; sh_rem = padv - accum; found = 1; }
        else accum += cn;
      }
    }
  }
  __syncthreads();
  const unsigned hb = sh_chosen, rem = sh_rem;
  if (t < 256) hist[t] = 0;
  __syncthreads();
#pragma unroll
  for (int j = 0; j < 32; ++j)
    if (live & (1u << j)) {
      int n = j * 1024 + t;
      if ((unsigned)(n >> 7) == hb) atomicAdd(&hist[n & 127], 1u);
    }
  __syncthreads();
  if (t == 0) {
    unsigned accum = 0;
    int found = 0;
    for (int b = 0; b < 128; ++b) {
      unsigned cn = hist[b];
      if (!found) {
        if (accum + cn >= rem) { sh_x = (hb << 7) | (unsigned)b; found = 1; }
        else accum += cn;
      }
    }
  }
  __syncthreads();
  const int X = (int)sh_x;
#pragma unroll
  for (int j = 0; j < 32; ++j)
    if (live & (1u << j)) {
      int n = j * 1024 + t;
      if (n <= X) {
        unsigned p = atomicAdd(&sh_pos, 1u);
        tok_idx[e * CAP + p] = n;
        expw[e * CAP + p] = expf(dec_f(key[j]) - m) * invZ;
      }
    }
  if (e == 0 && t == 0) { auxout[0] = 2.44140625e-4f; auxout[1] = 0.015625f; }
}

// ---------------- prep: f32 -> bf16 cast ----------------
__global__ __launch_bounds__(256)
void cvt_bf16_kernel(const float* __restrict__ in, u16* __restrict__ outp) {
  size_t i = ((size_t)blockIdx.x * 256 + threadIdx.x) * 8;
  float4 v0 = *(const float4*)(in + i);
  float4 v1 = *(const float4*)(in + i + 4);
  uint4 o;
  o.x = f2bf(v0.x) | ((unsigned)f2bf(v0.y) << 16);
  o.y = f2bf(v0.z) | ((unsigned)f2bf(v0.w) << 16);
  o.z = f2bf(v1.x) | ((unsigned)f2bf(v1.y) << 16);
  o.w = f2bf(v1.z) | ((unsigned)f2bf(v1.w) << 16);
  *(uint4*)(outp + i) = o;
}

// ---------------- prep: per-expert transpose+cvt: f32 [E][R][C] -> bf16 [E][C][R] ----------------
__global__ __launch_bounds__(256)
void transpose_cvt_kernel(const float* __restrict__ in, u16* __restrict__ outp,
                          int R, int C) {
  __shared__ u16 tile[64][66];
  const int e = blockIdx.z;
  const int r0 = blockIdx.y * 64, c0 = blockIdx.x * 64;
  const int t = threadIdx.x;
  {
    const int r = t >> 2, cs = (t & 3) * 16;
    const float* ip = in + ((size_t)e * R + (r0 + r)) * C + c0 + cs;
#pragma unroll
    for (int q = 0; q < 4; ++q) {
      float4 v = *(const float4*)(ip + q * 4);
      tile[r][cs + q * 4 + 0] = f2bf(v.x);
      tile[r][cs + q * 4 + 1] = f2bf(v.y);
      tile[r][cs + q * 4 + 2] = f2bf(v.z);
      tile[r][cs + q * 4 + 3] = f2bf(v.w);
    }
  }
  __syncthreads();
  {
    const int c = t >> 2, rs = (t & 3) * 16;
    u16* op = outp + ((size_t)e * C + (c0 + c)) * R + r0 + rs;
    uint4 o0, o1;
    o0.x = tile[rs + 0][c]  | ((unsigned)tile[rs + 1][c]  << 16);
    o0.y = tile[rs + 2][c]  | ((unsigned)tile[rs + 3][c]  << 16);
    o0.z = tile[rs + 4][c]  | ((unsigned)tile[rs + 5][c]  << 16);
    o0.w = tile[rs + 6][c]  | ((unsigned)tile[rs + 7][c]  << 16);
    o1.x = tile[rs + 8][c]  | ((unsigned)tile[rs + 9][c]  << 16);
    o1.y = tile[rs + 10][c] | ((unsigned)tile[rs + 11][c] << 16);
    o1.z = tile[rs + 12][c] | ((unsigned)tile[rs + 13][c] << 16);
    o1.w = tile[rs + 14][c] | ((unsigned)tile[rs + 15][c] << 16);
    *(uint4*)(op) = o0;
    *(uint4*)(op + 8) = o1;
  }
}

// ===================== bf16 GEMMs: BM128 x BN256, 3-buffer depth-2 pipeline, 2 phases/K-tile =====================
// 8 waves (512 thr), per-wave C = 64x64 (acc[4][4]). Stage 6 gl16/K-tile/wave; vmcnt(6) gate.
#define A_EL 8192      // 128*64
#define B_EL 16384     // 256*64

#define PHASE_MFMA(NJOFF) \
  __builtin_amdgcn_s_barrier(); \
  __builtin_amdgcn_s_setprio(1); \
  _Pragma("unroll") \
  for (int mi = 0; mi < 4; ++mi) \
    _Pragma("unroll") \
    for (int ni = 0; ni < 2; ++ni) \
      _Pragma("unroll") \
      for (int ks = 0; ks < 2; ++ks) \
        acc[mi][(NJOFF) + ni] = __builtin_amdgcn_mfma_f32_16x16x32_bf16( \
            af[mi][ks], bf[ni][ks], acc[mi][(NJOFF) + ni], 0, 0, 0); \
  __builtin_amdgcn_s_setprio(0); \
  __builtin_amdgcn_s_barrier();

#define STG6(rlo, rhi, bs, k0) do { \
  u16* Ad_ = AsmF + (bs) * A_EL; \
  u16* Bd_ = BsmF + (bs) * B_EL; \
  _Pragma("unroll") \
  for (int r = (rlo); r <= (rhi); ++r) \
    gl16(sSrc[r] + (k0), (r < 2 ? Ad_ : Bd_) + dOff[r]); \
} while (0)

__global__ __launch_bounds__(512, 2)
void fc1_bf(const u16* __restrict__ xb, const int* __restrict__ tok_idx,
            const u16* __restrict__ w1t, const float* __restrict__ b1,
            u16* __restrict__ h) {
  const int p = blockIdx.x;
  const int l = (p & 7) * 128 + (p >> 3);        // bijective XCD remap (1024 = 8*128)
  const int e  = l >> 4;
  const int mt = (l >> 2) & 3;
  const int nt = l & 3;
  const int m0 = mt * 128, n0 = nt * 256;
  const int t = threadIdx.x;
  const int lane = t & 63, wave = t >> 6;        // 8 waves
  const int wm = wave >> 2, wn = wave & 3;       // 2m x 4n, per-wave C 64x64

  __shared__ __align__(16) u16 AsmF[3 * A_EL];   // 48 KB
  __shared__ __align__(16) u16 BsmF[3 * B_EL];   // 96 KB

  const int gk = ((lane & 7) ^ (lane >> 3)) * 8; // inverse-swizzled k elem offset
  const int rsub = lane >> 3;

  const u16* sSrc[6];
  int dOff[6];
#pragma unroll
  for (int r = 0; r < 6; ++r) {
    const int c = r * 8 + wave;                  // 0..47
    if (r < 2) {                                 // A chunks 0..15 (rows 0..127, gathered)
      const int arow = c * 8 + rsub;
      const int tok = tok_idx[e * CAP + m0 + arow];
      sSrc[r] = xb + (size_t)tok * DIM + gk;
      dOff[r] = c * 512;
    } else {                                     // B chunks 0..31 (rows 0..255)
      const int brow = (c - 16) * 8 + rsub;
      sSrc[r] = w1t + ((size_t)e * HID + n0 + brow) * DIM + gk;
      dOff[r] = (c - 16) * 512;
    }
  }

  f32x4 acc[4][4] = {};
  const int lr = lane & 15, hi4 = lane >> 4;

  STG6(0, 5, 0, 0);     // K-tile 0 -> buf 0
  STG6(0, 5, 1, 64);    // K-tile 1 -> buf 1
  int cur = 0, stg = 2;
  for (int tt = 0; tt < 8; ++tt) {               // KT = DIM/64 = 8
    if (tt < 7) asm volatile("s_waitcnt vmcnt(6)" ::: "memory");
    else        asm volatile("s_waitcnt vmcnt(0)" ::: "memory");
    __builtin_amdgcn_s_barrier();
    const u16* Ab = AsmF + cur * A_EL;
    const u16* Bb = BsmF + cur * B_EL;
    const int k2 = (tt + 2) * 64;
    bf16x8 af[4][2], bf[2][2];
#pragma unroll
    for (int mi = 0; mi < 4; ++mi)
#pragma unroll
      for (int ks = 0; ks < 2; ++ks) {
        const int row = wm * 64 + mi * 16 + lr;
        const int kb = ks * 64 + hi4 * 16;
        af[mi][ks] = *(const bf16x8*)((const char*)Ab + row * 128 + (kb ^ ((row & 7) << 4)));
      }
#pragma unroll
    for (int ni = 0; ni < 2; ++ni)
#pragma unroll
      for (int ks = 0; ks < 2; ++ks) {
        const int row = wn * 64 + ni * 16 + lr;
        const int kb = ks * 64 + hi4 * 16;
        bf[ni][ks] = *(const bf16x8*)((const char*)Bb + row * 128 + (kb ^ ((row & 7) << 4)));
      }
    if (tt < 6) STG6(0, 2, stg, k2);
    PHASE_MFMA(0)
    // phase 1: nh=1
#pragma unroll
    for (int ni = 0; ni < 2; ++ni)
#pragma unroll
      for (int ks = 0; ks < 2; ++ks) {
        const int row = wn * 64 + 32 + ni * 16 + lr;
        const int kb = ks * 64 + hi4 * 16;
        bf[ni][ks] = *(const bf16x8*)((const char*)Bb + row * 128 + (kb ^ ((row & 7) << 4)));
      }
    if (tt < 6) STG6(3, 5, stg, k2);
    PHASE_MFMA(2)
    cur = cur == 2 ? 0 : cur + 1;
    stg = stg == 2 ? 0 : stg + 1;
  }

  const int lq = lane >> 4, lc = lane & 15;
#pragma unroll
  for (int nj = 0; nj < 4; ++nj) {
    const int n_l = wn * 64 + nj * 16 + lc;
    const float bias = b1[e * HID + n0 + n_l];
#pragma unroll
    for (int mi = 0; mi < 4; ++mi) {
#pragma unroll
      for (int j = 0; j < 4; ++j) {
        const int m_l = wm * 64 + mi * 16 + lq * 4 + j;
        float v = acc[mi][nj][j] + bias;
        h[((size_t)(e * CAP + m0 + m_l)) * HID + (n0 + n_l)] = f2bf(gelu_f(v));
      }
    }
  }
}

__global__ __launch_bounds__(512, 2)
void fc2_bf(const u16* __restrict__ h, const u16* __restrict__ w2t,
            const float* __restrict__ b2, const int* __restrict__ tok_idx,
            const float* __restrict__ expw, float* __restrict__ out) {
  const int p = blockIdx.x;
  const int l = (p & 7) * 64 + (p >> 3);         // bijective XCD remap (512 = 8*64)
  const int e  = l >> 3;
  const int mt = (l >> 1) & 3;
  const int nt = l & 1;
  const int m0 = mt * 128, n0 = nt * 256;
  const int t = threadIdx.x;
  const int lane = t & 63, wave = t >> 6;
  const int wm = wave >> 2, wn = wave & 3;

  __shared__ __align__(16) u16 AsmF[3 * A_EL];
  __shared__ __align__(16) u16 BsmF[3 * B_EL];

  const int gk = ((lane & 7) ^ (lane >> 3)) * 8;
  const int rsub = lane >> 3;

  const u16* sSrc[6];
  int dOff[6];
#pragma unroll
  for (int r = 0; r < 6; ++r) {
    const int c = r * 8 + wave;
    if (r < 2) {
      const int arow = c * 8 + rsub;
      sSrc[r] = h + ((size_t)(e * CAP + m0 + arow)) * HID + gk;
      dOff[r] = c * 512;
    } else {
      const int brow = (c - 16) * 8 + rsub;
      sSrc[r] = w2t + ((size_t)e * DIM + n0 + brow) * HID + gk;
      dOff[r] = (c - 16) * 512;
    }
  }

  f32x4 acc[4][4] = {};
  const int lr = lane & 15, hi4 = lane >> 4;

  STG6(0, 5, 0, 0);
  STG6(0, 5, 1, 64);
  int cur = 0, stg = 2;
  for (int tt = 0; tt < 16; ++tt) {              // KT = HID/64 = 16
    if (tt < 15) asm volatile("s_waitcnt vmcnt(6)" ::: "memory");
    else         asm volatile("s_waitcnt vmcnt(0)" ::: "memory");
    __builtin_amdgcn_s_barrier();
    const u16* Ab = AsmF + cur * A_EL;
    const u16* Bb = BsmF + cur * B_EL;
    const int k2 = (tt + 2) * 64;
    bf16x8 af[4][2], bf[2][2];
#pragma unroll
    for (int mi = 0; mi < 4; ++mi)
#pragma unroll
      for (int ks = 0; ks < 2; ++ks) {
        const int row = wm * 64 + mi * 16 + lr;
        const int kb = ks * 64 + hi4 * 16;
        af[mi][ks] = *(const bf16x8*)((const char*)Ab + row * 128 + (kb ^ ((row & 7) << 4)));
      }
#pragma unroll
    for (int ni = 0; ni < 2; ++ni)
#pragma unroll
      for (int ks = 0; ks < 2; ++ks) {
        const int row = wn * 64 + ni * 16 + lr;
        const int kb = ks * 64 + hi4 * 16;
        bf[ni][ks] = *(const bf16x8*)((const char*)Bb + row * 128 + (kb ^ ((row & 7) << 4)));
      }
    if (tt < 14) STG6(0, 2, stg, k2);
    PHASE_MFMA(0)
#pragma unroll
    for (int ni = 0; ni < 2; ++ni)
#pragma unroll
      for (int ks = 0; ks < 2; ++ks) {
        const int row = wn * 64 + 32 + ni * 16 + lr;
        const int kb = ks * 64 + hi4 * 16;
        bf[ni][ks] = *(const bf16x8*)((const char*)Bb + row * 128 + (kb ^ ((row & 7) << 4)));
      }
    if (tt < 14) STG6(3, 5, stg, k2);
    PHASE_MFMA(2)
    cur = cur == 2 ? 0 : cur + 1;
    stg = stg == 2 ? 0 : stg + 1;
  }

  const int lq = lane >> 4, lc = lane & 15;
  int   tokm[4][4];
  float wgt[4][4];
#pragma unroll
  for (int mi = 0; mi < 4; ++mi)
#pragma unroll
    for (int j = 0; j < 4; ++j) {
      const int m_l = wm * 64 + mi * 16 + lq * 4 + j;
      tokm[mi][j] = tok_idx[e * CAP + m0 + m_l];
      wgt[mi][j]  = expw[e * CAP + m0 + m_l];
    }
#pragma unroll
  for (int nj = 0; nj < 4; ++nj) {
    const int n_l = wn * 64 + nj * 16 + lc;
    const float bias = b2[e * DIM + n0 + n_l];
#pragma unroll
    for (int mi = 0; mi < 4; ++mi)
#pragma unroll
      for (int j = 0; j < 4; ++j) {
        float v = (acc[mi][nj][j] + bias) * wgt[mi][j];
        atomicAdd(out + (size_t)tokm[mi][j] * DIM + (n0 + n_l), v);
      }
  }
}

// ===================== fallback f32-input GEMMs (ws too small) =====================
#define SWZ(row, cb) ((cb) ^ (((((row) >> 3) ^ (row)) & 7) << 4))

__global__ __launch_bounds__(256)
void fc1_kernel(const float* __restrict__ x, const int* __restrict__ tok_idx,
                const float* __restrict__ w1, const float* __restrict__ b1,
                u16* __restrict__ h) {
  const int bx = blockIdx.x;
  const int e  = bx >> 5;
  const int mt = (bx >> 3) & 3;
  const int nt = bx & 7;
  const int m0 = mt * 128, n0 = nt * 128;
  const int t = threadIdx.x;
  const int lane = t & 63, wave = t >> 6;
  const int wm = wave >> 1, wn = wave & 1;

  __shared__ __align__(16) u16 Asm[128 * 64];
  __shared__ __align__(16) u16 Bsm[128 * 64];

  const int arq = t & 31, akq = t >> 5;
  int tokr[4];
#pragma unroll
  for (int j = 0; j < 4; ++j) tokr[j] = tok_idx[e * CAP + m0 + arq * 4 + j];
  const int nq = t & 31, kq = t >> 5;
  const float* bptr = w1 + (size_t)e * DIM * HID + n0 + nq * 4;

  f32x4 acc[4][4] = {};

  for (int k0 = 0; k0 < DIM; k0 += 64) {
    float4 av0[4], av1[4];
#pragma unroll
    for (int j = 0; j < 4; ++j) {
      const float* ap = x + (size_t)tokr[j] * DIM + k0 + akq * 8;
      av0[j] = *(const float4*)(ap);
      av1[j] = *(const float4*)(ap + 4);
    }
    float4 bv[8];
#pragma unroll
    for (int kk = 0; kk < 8; ++kk)
      bv[kk] = *(const float4*)(bptr + (size_t)(k0 + kq * 8 + kk) * HID);
    __syncthreads();
#pragma unroll
    for (int j = 0; j < 4; ++j) {
      const int row = arq * 4 + j;
      ushort4 w0, w1v;
      w0.x = f2bf(av0[j].x); w0.y = f2bf(av0[j].y); w0.z = f2bf(av0[j].z); w0.w = f2bf(av0[j].w);
      w1v.x = f2bf(av1[j].x); w1v.y = f2bf(av1[j].y); w1v.z = f2bf(av1[j].z); w1v.w = f2bf(av1[j].w);
      *(ushort4*)((char*)Asm + row * 128 + SWZ(row, (akq * 8 + 0) * 2)) = w0;
      *(ushort4*)((char*)Asm + row * 128 + SWZ(row, (akq * 8 + 4) * 2)) = w1v;
    }
#pragma unroll
    for (int g = 0; g < 2; ++g) {
#pragma unroll
      for (int j = 0; j < 4; ++j) {
        ushort4 wv;
        wv.x = f2bf(GET4(bv[g * 4 + 0], j));
        wv.y = f2bf(GET4(bv[g * 4 + 1], j));
        wv.z = f2bf(GET4(bv[g * 4 + 2], j));
        wv.w = f2bf(GET4(bv[g * 4 + 3], j));
        const int row = nq * 4 + j;
        const int cb = (kq * 8 + g * 4) * 2;
        *(ushort4*)((char*)Bsm + row * 128 + SWZ(row, cb)) = wv;
      }
    }
    __syncthreads();
#pragma unroll
    for (int ks = 0; ks < 2; ++ks) {
      bf16x8 af[4], bf[4];
#pragma unroll
      for (int mi = 0; mi < 4; ++mi) {
        const int row = wm * 64 + mi * 16 + (lane & 15);
        const int cb = ks * 64 + (lane >> 4) * 16;
        af[mi] = *(const bf16x8*)((const char*)Asm + row * 128 + SWZ(row, cb));
      }
#pragma unroll
      for (int ni = 0; ni < 4; ++ni) {
        const int row = wn * 64 + ni * 16 + (lane & 15);
        const int cb = ks * 64 + (lane >> 4) * 16;
        bf[ni] = *(const bf16x8*)((const char*)Bsm + row * 128 + SWZ(row, cb));
      }
#pragma unroll
      for (int mi = 0; mi < 4; ++mi)
#pragma unroll
        for (int ni = 0; ni < 4; ++ni)
          acc[mi][ni] = __builtin_amdgcn_mfma_f32_16x16x32_bf16(af[mi], bf[ni], acc[mi][ni], 0, 0, 0);
    }
  }
  const int lq = lane >> 4, lc = lane & 15;
#pragma unroll
  for (int ni = 0; ni < 4; ++ni) {
    const int n_l = wn * 64 + ni * 16 + lc;
    const float bias = b1[e * HID + n0 + n_l];
#pragma unroll
    for (int mi = 0; mi < 4; ++mi) {
#pragma unroll
      for (int j = 0; j < 4; ++j) {
        const int m_l = wm * 64 + mi * 16 + lq * 4 + j;
        float v = acc[mi][ni][j] + bias;
        h[((size_t)(e * CAP + m0 + m_l)) * HID + (n0 + n_l)] = f2bf(gelu_f(v));
      }
    }
  }
}

__global__ __launch_bounds__(256)
void fc2_kernel(const u16* __restrict__ h, const float* __restrict__ w2,
                const float* __restrict__ b2, const int* __restrict__ tok_idx,
                const float* __restrict__ expw, float* __restrict__ out) {
  const int bx = blockIdx.x;
  const int e  = bx >> 4;
  const int mt = (bx >> 2) & 3;
  const int nt = bx & 3;
  const int m0 = mt * 128, n0 = nt * 128;
  const int t = threadIdx.x;
  const int lane = t & 63, wave = t >> 6;
  const int wm = wave >> 1, wn = wave & 1;

  __shared__ __align__(16) u16 Asm[128 * 64];
  __shared__ __align__(16) u16 Bsm[128 * 64];

  const int arq = t & 31, akq = t >> 5;
  const u16* aptr0 = h + ((size_t)(e * CAP + m0 + arq * 4)) * HID + akq * 8;
  const int nq = t & 31, kq = t >> 5;
  const float* bptr = w2 + (size_t)e * HID * DIM + n0 + nq * 4;

  f32x4 acc[4][4] = {};

  for (int k0 = 0; k0 < HID; k0 += 64) {
    uint4 av[4];
#pragma unroll
    for (int j = 0; j < 4; ++j)
      av[j] = *(const uint4*)(aptr0 + (size_t)j * HID + k0);
    float4 bv[8];
#pragma unroll
    for (int kk = 0; kk < 8; ++kk)
      bv[kk] = *(const float4*)(bptr + (size_t)(k0 + kq * 8 + kk) * DIM);
    __syncthreads();
#pragma unroll
    for (int j = 0; j < 4; ++j) {
      const int row = arq * 4 + j;
      *(uint4*)((char*)Asm + row * 128 + SWZ(row, akq * 16)) = av[j];
    }
#pragma unroll
    for (int g = 0; g < 2; ++g) {
#pragma unroll
      for (int j = 0; j < 4; ++j) {
        ushort4 wv;
        wv.x = f2bf(GET4(bv[g * 4 + 0], j));
        wv.y = f2bf(GET4(bv[g * 4 + 1], j));
        wv.z = f2bf(GET4(bv[g * 4 + 2], j));
        wv.w = f2bf(GET4(bv[g * 4 + 3], j));
        const int row = nq * 4 + j;
        const int cb = (kq * 8 + g * 4) * 2;
        *(ushort4*)((char*)Bsm + row * 128 + SWZ(row, cb)) = wv;
      }
    }
    __syncthreads();
#pragma unroll
    for (int ks = 0; ks < 2; ++ks) {
      bf16x8 af[4], bf[4];
#pragma unroll
      for (int mi = 0; mi < 4; ++mi) {
        const int row = wm * 64 + mi * 16 + (lane & 15);
        const int cb = ks * 64 + (lane >> 4) * 16;
        af[mi] = *(const bf16x8*)((const char*)Asm + row * 128 + SWZ(row, cb));
      }
#pragma unroll
      for (int ni = 0; ni < 4; ++ni) {
        const int row = wn * 64 + ni * 16 + (lane & 15);
        const int cb = ks * 64 + (lane >> 4) * 16;
        bf[ni] = *(const bf16x8*)((const char*)Bsm + row * 128 + SWZ(row, cb));
      }
#pragma unroll
      for (int mi = 0; mi < 4; ++mi)
#pragma unroll
        for (int ni = 0; ni < 4; ++ni)
          acc[mi][ni] = __builtin_amdgcn_mfma_f32_16x16x32_bf16(af[mi], bf[ni], acc[mi][ni], 0, 0, 0);
    }
  }
  const int lq = lane >> 4, lc = lane & 15;
  int   tokm[4][4];
  float wgt[4][4];
#pragma unroll
  for (int mi = 0; mi < 4; ++mi)
#pragma unroll
    for (int j = 0; j < 4; ++j) {
      const int m_l = wm * 64 + mi * 16 + lq * 4 + j;
      tokm[mi][j] = tok_idx[e * CAP + m0 + m_l];
      wgt[mi][j]  = expw[e * CAP + m0 + m_l];
    }
#pragma unroll
  for (int ni = 0; ni < 4; ++ni) {
    const int n_l = wn * 64 + ni * 16 + lc;
    const float bias = b2[e * DIM + n0 + n_l];
#pragma unroll
    for (int mi = 0; mi < 4; ++mi)
#pragma unroll
      for (int j = 0; j < 4; ++j) {
        float v = (acc[mi][ni][j] + bias) * wgt[mi][j];
        atomicAdd(out + (size_t)tokm[mi][j] * DIM + (n0 + n_l), v);
      }
  }
}

extern "C" void kernel_launch(void* const* d_in, const int* in_sizes, int n_in,
                              void* d_out, int out_size, void* d_ws, size_t ws_size,
                              hipStream_t stream) {
  const float* x  = (const float*)d_in[0];
  const float* rw = (const float*)d_in[1];
  const float* w1 = (const float*)d_in[2];
  const float* b1 = (const float*)d_in[3];
  const float* w2 = (const float*)d_in[4];
  const float* b2 = (const float*)d_in[5];
  float* out = (float*)d_out;

  char* ws = (char*)d_ws;
  const size_t MB = 1u << 20;
  float* logits = (float*)ws;                                   // [0, 8M)
  int*   toki   = (int*)(ws + 8 * MB);                          // 128 KB
  float* ew     = (float*)(ws + 8 * MB + (128u << 10));         // 128 KB

  (void)hipMemsetAsync(d_out, 0, (size_t)out_size * sizeof(float), stream);
  router_kernel<<<dim3(1024), dim3(256), 0, stream>>>(x, rw, logits);
  topk_kernel<<<dim3(64), dim3(1024), 0, stream>>>(logits, toki, ew, out + (size_t)N_TOK * DIM);

  const size_t off_xb = 8 * MB + (256u << 10);   // 8.25M
  const size_t off_wt = off_xb + 32 * MB;        // 40.25M
  const size_t off_h  = off_wt + 64 * MB;        // 104.25M
  const size_t need   = off_h + 64 * MB;         // 168.25M

  if (ws_size >= need) {
    u16* xb  = (u16*)(ws + off_xb);
    u16* wt  = (u16*)(ws + off_wt);
    u16* h   = (u16*)(ws + off_h);
    cvt_bf16_kernel<<<dim3(8192), dim3(256), 0, stream>>>(x, xb);
    transpose_cvt_kernel<<<dim3(16, 8, 64), dim3(256), 0, stream>>>(w1, wt, 512, 1024);
    fc1_bf<<<dim3(1024), dim3(512), 0, stream>>>(xb, toki, wt, b1, h);
    transpose_cvt_kernel<<<dim3(8, 16, 64), dim3(256), 0, stream>>>(w2, wt, 1024, 512);
    fc2_bf<<<dim3(512), dim3(512), 0, stream>>>(h, wt, b2, toki, ew, out);
  } else {
    u16* h = (u16*)(ws + 8 * MB + (256u << 10)); // old layout
    fc1_kernel<<<dim3(2048), dim3(256), 0, stream>>>(x, toki, w1, b1, h);
    fc2_kernel<<<dim3(1024), dim3(256), 0, stream>>>(h, w2, b2, toki, ew, out);
  }
}

// Round 12
// 415.297 us; speedup vs baseline: 1.3521x; 1.2062x over previous
//
#include <hip/hip_runtime.h>
#include <math.h>

#define N_TOK 32768
#define DIM   512
#define NEXP  64
#define HID   1024
#define CAP   512

typedef float  f32x4  __attribute__((ext_vector_type(4)));
typedef short  bf16x8 __attribute__((ext_vector_type(8)));
typedef unsigned short u16;

#define GET4(v, jj) ((jj) == 0 ? (v).x : (jj) == 1 ? (v).y : (jj) == 2 ? (v).z : (v).w)

__device__ __forceinline__ u16 f2bf(float f) {
  unsigned u = __float_as_uint(f);
  u += 0x7FFFu + ((u >> 16) & 1u);   // RNE
  return (u16)(u >> 16);
}
__device__ __forceinline__ unsigned enc_f(float f) {  // monotone f32 -> u32
  unsigned u = __float_as_uint(f);
  return (u & 0x80000000u) ? ~u : (u | 0x80000000u);
}
__device__ __forceinline__ float dec_f(unsigned k) {
  unsigned u = (k & 0x80000000u) ? (k & 0x7FFFFFFFu) : ~k;
  return __uint_as_float(u);
}
__device__ __forceinline__ void gl16(const u16* g, u16* l) {
  __builtin_amdgcn_global_load_lds(
      (const __attribute__((address_space(1))) unsigned int*)g,
      (__attribute__((address_space(3))) unsigned int*)l, 16, 0, 0);
}
// exact-enough erf (A&S 7.1.26, |eps|<=1.5e-7) -> gelu
__device__ __forceinline__ float gelu_f(float v) {
  float x = fabsf(v) * 0.70710678118654752f;
  float tt = 1.0f / (1.0f + 0.3275911f * x);
  float poly = tt * (0.254829592f + tt * (-0.284496736f + tt * (1.421413741f +
               tt * (-1.453152027f + tt * 1.061405429f))));
  float erfabs = 1.0f - poly * __expf(-x * x);
  float erfv = v >= 0.f ? erfabs : -erfabs;
  return 0.5f * v * (1.0f + erfv);
}

// ---------------- router: LDS-tiled fp32 SGEMM, 64 tok x 64 exp per block ----------------
// Also emits xb = bf16(x) as a by-product (each x element is read exactly once here).
__global__ __launch_bounds__(256)
void router_kernel(const float* __restrict__ x, const float* __restrict__ rw,
                   float* __restrict__ logitsT, u16* __restrict__ xb) {
  __shared__ float As[32][68];   // [k][m], pad 68 for bank spread
  __shared__ float Bs[32][68];   // [k][e]
  const int t = threadIdx.x;
  const int n0 = blockIdx.x * 64;
  const int ty = t >> 4, tx = t & 15;        // 16x16 thread grid, 4x4 out each
  const int am = t >> 2, akq = (t & 3) * 8;  // A-load: row m, 8 k-elems
  const int bk = t >> 3, beq = (t & 7) * 8;  // B-load: row k, 8 e-elems
  const float* xrow = x + (size_t)(n0 + am) * DIM + akq;
  u16* xbrow = xb ? (xb + (size_t)(n0 + am) * DIM + akq) : (u16*)0;
  const float* brow = rw + (size_t)bk * NEXP + beq;

  float acc[4][4] = {};
  for (int k0 = 0; k0 < DIM; k0 += 32) {
    float4 a0 = *(const float4*)(xrow + k0);
    float4 a1 = *(const float4*)(xrow + k0 + 4);
    float4 b0 = *(const float4*)(brow + (size_t)k0 * NEXP);
    float4 b1 = *(const float4*)(brow + (size_t)k0 * NEXP + 4);
    if (xbrow) {
      uint4 o;
      o.x = f2bf(a0.x) | ((unsigned)f2bf(a0.y) << 16);
      o.y = f2bf(a0.z) | ((unsigned)f2bf(a0.w) << 16);
      o.z = f2bf(a1.x) | ((unsigned)f2bf(a1.y) << 16);
      o.w = f2bf(a1.z) | ((unsigned)f2bf(a1.w) << 16);
      *(uint4*)(xbrow + k0) = o;
    }
    __syncthreads();   // prev-tile compute done before overwrite
    As[akq + 0][am] = a0.x; As[akq + 1][am] = a0.y;
    As[akq + 2][am] = a0.z; As[akq + 3][am] = a0.w;
    As[akq + 4][am] = a1.x; As[akq + 5][am] = a1.y;
    As[akq + 6][am] = a1.z; As[akq + 7][am] = a1.w;
    *(float4*)&Bs[bk][beq] = b0;
    *(float4*)&Bs[bk][beq + 4] = b1;
    __syncthreads();
#pragma unroll
    for (int k = 0; k < 32; ++k) {
      float4 av = *(const float4*)&As[k][ty * 4];
      float4 bv = *(const float4*)&Bs[k][tx * 4];
#pragma unroll
      for (int i = 0; i < 4; ++i)
#pragma unroll
        for (int j = 0; j < 4; ++j)
          acc[i][j] += GET4(av, i) * GET4(bv, j);
    }
  }
#pragma unroll
  for (int j = 0; j < 4; ++j) {
    float4 o; o.x = acc[0][j]; o.y = acc[1][j]; o.z = acc[2][j]; o.w = acc[3][j];
    *(float4*)(logitsT + (size_t)(tx * 4 + j) * N_TOK + n0 + ty * 4) = o;
  }
}

// ------------- topk -------------
__global__ __launch_bounds__(1024)
void topk_kernel(const float* __restrict__ logitsT, int* __restrict__ tok_idx,
                 float* __restrict__ expw, float* __restrict__ auxout) {
  const int e = blockIdx.x;
  const int t = threadIdx.x;
  const float* row = logitsT + (size_t)e * N_TOK;

  unsigned key[32];          // token n = j*1024 + t
#pragma unroll
  for (int j = 0; j < 32; ++j) key[j] = enc_f(row[j * 1024 + t]);

  __shared__ unsigned ured[1024];
  __shared__ float    fred[1024];
  __shared__ unsigned hist[256];
  __shared__ unsigned sh_chosen, sh_rem, sh_x, sh_pos;

  unsigned km = 0;
#pragma unroll
  for (int j = 0; j < 32; ++j) km = key[j] > km ? key[j] : km;
  ured[t] = km;
  __syncthreads();
  for (int s = 512; s > 0; s >>= 1) {
    if (t < s) { unsigned o = ured[t + s]; if (o > ured[t]) ured[t] = o; }
    __syncthreads();
  }
  const float m = dec_f(ured[0]);

  float ssum = 0.f;
#pragma unroll
  for (int j = 0; j < 32; ++j) ssum += expf(dec_f(key[j]) - m);
  fred[t] = ssum;
  __syncthreads();
  for (int s = 512; s > 0; s >>= 1) {
    if (t < s) fred[t] += fred[t + s];
    __syncthreads();
  }
  const float invZ = 1.0f / fred[0];

  if (t == 0) sh_rem = CAP;
  __syncthreads();
  unsigned live = 0xFFFFFFFFu;
  unsigned prefix = 0;
  for (int pass = 0; pass < 4; ++pass) {
    const int shift = 24 - pass * 8;
    if (t < 256) hist[t] = 0;
    __syncthreads();
#pragma unroll
    for (int j = 0; j < 32; ++j)
      if (live & (1u << j)) atomicAdd(&hist[(key[j] >> shift) & 0xFFu], 1u);
    __syncthreads();
    if (t == 0) {
      unsigned need = sh_rem, accum = 0;
      int found = 0;
      for (int b = 255; b >= 0; --b) {
        unsigned cn = hist[b];
        if (!found) {
          if (accum + cn >= need) { sh_chosen = (unsigned)b; sh_rem = need - accum; found = 1; }
          else accum += cn;
        }
      }
    }
    __syncthreads();
    const unsigned ch = sh_chosen;
#pragma unroll
    for (int j = 0; j < 32; ++j)
      if (((key[j] >> shift) & 0xFFu) != ch) live &= ~(1u << j);
    prefix = (prefix << 8) | ch;
    __syncthreads();
  }
  const unsigned ustar = prefix;

  if (t == 0) sh_pos = 0;
  __syncthreads();
#pragma unroll
  for (int j = 0; j < 32; ++j) {
    if (key[j] > ustar) {
      unsigned p = atomicAdd(&sh_pos, 1u);
      tok_idx[e * CAP + p] = j * 1024 + t;
      expw[e * CAP + p] = expf(dec_f(key[j]) - m) * invZ;
    }
  }
  __syncthreads();
  const unsigned padv = CAP - sh_pos;

  if (t < 256) hist[t] = 0;
  __syncthreads();
#pragma unroll
  for (int j = 0; j < 32; ++j)
    if (live & (1u << j)) atomicAdd(&hist[(j * 1024 + t) >> 7], 1u);
  __syncthreads();
  if (t == 0) {
    unsigned accum = 0;
    int found = 0;
    for (int b = 0; b < 256; ++b) {
      unsigned cn = hist[b];
      if (!found) {
        if (accum + cn >= padv) { sh_chosen = (unsigned)b; sh_rem = padv - accum; found = 1; }
        else accum += cn;
      }
    }
  }
  __syncthreads();
  const unsigned hb = sh_chosen, rem = sh_rem;
  if (t < 256) hist[t] = 0;
  __syncthreads();
#pragma unroll
  for (int j = 0; j < 32; ++j)
    if (live & (1u << j)) {
      int n = j * 1024 + t;
      if ((unsigned)(n >> 7) == hb) atomicAdd(&hist[n & 127], 1u);
    }
  __syncthreads();
  if (t == 0) {
    unsigned accum = 0;
    int found = 0;
    for (int b = 0; b < 128; ++b) {
      unsigned cn = hist[b];
      if (!found) {
        if (accum + cn >= rem) { sh_x = (hb << 7) | (unsigned)b; found = 1; }
        else accum += cn;
      }
    }
  }
  __syncthreads();
  const int X = (int)sh_x;
#pragma unroll
  for (int j = 0; j < 32; ++j)
    if (live & (1u << j)) {
      int n = j * 1024 + t;
      if (n <= X) {
        unsigned p = atomicAdd(&sh_pos, 1u);
        tok_idx[e * CAP + p] = n;
        expw[e * CAP + p] = expf(dec_f(key[j]) - m) * invZ;
      }
    }
  if (e == 0 && t == 0) { auxout[0] = 2.44140625e-4f; auxout[1] = 0.015625f; }
}

// ---------------- prep: per-expert transpose+cvt: f32 [E][R][C] -> bf16 [E][C][R] ----------------
__global__ __launch_bounds__(256)
void transpose_cvt_kernel(const float* __restrict__ in, u16* __restrict__ outp,
                          int R, int C) {
  __shared__ u16 tile[64][66];
  const int e = blockIdx.z;
  const int r0 = blockIdx.y * 64, c0 = blockIdx.x * 64;
  const int t = threadIdx.x;
  {
    const int r = t >> 2, cs = (t & 3) * 16;
    const float* ip = in + ((size_t)e * R + (r0 + r)) * C + c0 + cs;
#pragma unroll
    for (int q = 0; q < 4; ++q) {
      float4 v = *(const float4*)(ip + q * 4);
      tile[r][cs + q * 4 + 0] = f2bf(v.x);
      tile[r][cs + q * 4 + 1] = f2bf(v.y);
      tile[r][cs + q * 4 + 2] = f2bf(v.z);
      tile[r][cs + q * 4 + 3] = f2bf(v.w);
    }
  }
  __syncthreads();
  {
    const int c = t >> 2, rs = (t & 3) * 16;
    u16* op = outp + ((size_t)e * C + (c0 + c)) * R + r0 + rs;
    uint4 o0, o1;
    o0.x = tile[rs + 0][c]  | ((unsigned)tile[rs + 1][c]  << 16);
    o0.y = tile[rs + 2][c]  | ((unsigned)tile[rs + 3][c]  << 16);
    o0.z = tile[rs + 4][c]  | ((unsigned)tile[rs + 5][c]  << 16);
    o0.w = tile[rs + 6][c]  | ((unsigned)tile[rs + 7][c]  << 16);
    o1.x = tile[rs + 8][c]  | ((unsigned)tile[rs + 9][c]  << 16);
    o1.y = tile[rs + 10][c] | ((unsigned)tile[rs + 11][c] << 16);
    o1.z = tile[rs + 12][c] | ((unsigned)tile[rs + 13][c] << 16);
    o1.w = tile[rs + 14][c] | ((unsigned)tile[rs + 15][c] << 16);
    *(uint4*)(op) = o0;
    *(uint4*)(op + 8) = o1;
  }
}

// ===================== bf16 GEMMs: BM128 x BN256, 3-buffer depth-2 pipeline, 2 phases/K-tile =====================
#define A_EL 8192      // 128*64
#define B_EL 16384     // 256*64

#define PHASE_MFMA(NJOFF) \
  __builtin_amdgcn_s_barrier(); \
  __builtin_amdgcn_s_setprio(1); \
  _Pragma("unroll") \
  for (int mi = 0; mi < 4; ++mi) \
    _Pragma("unroll") \
    for (int ni = 0; ni < 2; ++ni) \
      _Pragma("unroll") \
      for (int ks = 0; ks < 2; ++ks) \
        acc[mi][(NJOFF) + ni] = __builtin_amdgcn_mfma_f32_16x16x32_bf16( \
            af[mi][ks], bf[ni][ks], acc[mi][(NJOFF) + ni], 0, 0, 0); \
  __builtin_amdgcn_s_setprio(0); \
  __builtin_amdgcn_s_barrier();

#define STG6(rlo, rhi, bs, k0) do { \
  u16* Ad_ = AsmF + (bs) * A_EL; \
  u16* Bd_ = BsmF + (bs) * B_EL; \
  _Pragma("unroll") \
  for (int r = (rlo); r <= (rhi); ++r) \
    gl16(sSrc[r] + (k0), (r < 2 ? Ad_ : Bd_) + dOff[r]); \
} while (0)

__global__ __launch_bounds__(512, 2)
void fc1_bf(const u16* __restrict__ xb, const int* __restrict__ tok_idx,
            const u16* __restrict__ w1t, const float* __restrict__ b1,
            u16* __restrict__ h) {
  const int p = blockIdx.x;
  const int l = (p & 7) * 128 + (p >> 3);        // bijective XCD remap (1024 = 8*128)
  const int e  = l >> 4;
  const int mt = (l >> 2) & 3;
  const int nt = l & 3;
  const int m0 = mt * 128, n0 = nt * 256;
  const int t = threadIdx.x;
  const int lane = t & 63, wave = t >> 6;        // 8 waves
  const int wm = wave >> 2, wn = wave & 3;       // 2m x 4n, per-wave C 64x64

  __shared__ __align__(16) u16 AsmF[3 * A_EL];   // 48 KB
  __shared__ __align__(16) u16 BsmF[3 * B_EL];   // 96 KB

  const int gk = ((lane & 7) ^ (lane >> 3)) * 8; // inverse-swizzled k elem offset
  const int rsub = lane >> 3;

  const u16* sSrc[6];
  int dOff[6];
#pragma unroll
  for (int r = 0; r < 6; ++r) {
    const int c = r * 8 + wave;                  // 0..47
    if (r < 2) {                                 // A chunks 0..15 (rows 0..127, gathered)
      const int arow = c * 8 + rsub;
      const int tok = tok_idx[e * CAP + m0 + arow];
      sSrc[r] = xb + (size_t)tok * DIM + gk;
      dOff[r] = c * 512;
    } else {                                     // B chunks 0..31 (rows 0..255)
      const int brow = (c - 16) * 8 + rsub;
      sSrc[r] = w1t + ((size_t)e * HID + n0 + brow) * DIM + gk;
      dOff[r] = (c - 16) * 512;
    }
  }

  f32x4 acc[4][4] = {};
  const int lr = lane & 15, hi4 = lane >> 4;

  STG6(0, 5, 0, 0);     // K-tile 0 -> buf 0
  STG6(0, 5, 1, 64);    // K-tile 1 -> buf 1
  int cur = 0, stg = 2;
  for (int tt = 0; tt < 8; ++tt) {               // KT = DIM/64 = 8
    if (tt < 7) asm volatile("s_waitcnt vmcnt(6)" ::: "memory");
    else        asm volatile("s_waitcnt vmcnt(0)" ::: "memory");
    __builtin_amdgcn_s_barrier();
    const u16* Ab = AsmF + cur * A_EL;
    const u16* Bb = BsmF + cur * B_EL;
    const int k2 = (tt + 2) * 64;
    bf16x8 af[4][2], bf[2][2];
#pragma unroll
    for (int mi = 0; mi < 4; ++mi)
#pragma unroll
      for (int ks = 0; ks < 2; ++ks) {
        const int row = wm * 64 + mi * 16 + lr;
        const int kb = ks * 64 + hi4 * 16;
        af[mi][ks] = *(const bf16x8*)((const char*)Ab + row * 128 + (kb ^ ((row & 7) << 4)));
      }
#pragma unroll
    for (int ni = 0; ni < 2; ++ni)
#pragma unroll
      for (int ks = 0; ks < 2; ++ks) {
        const int row = wn * 64 + ni * 16 + lr;
        const int kb = ks * 64 + hi4 * 16;
        bf[ni][ks] = *(const bf16x8*)((const char*)Bb + row * 128 + (kb ^ ((row & 7) << 4)));
      }
    if (tt < 6) STG6(0, 2, stg, k2);
    PHASE_MFMA(0)
    // phase 1: nh=1
#pragma unroll
    for (int ni = 0; ni < 2; ++ni)
#pragma unroll
      for (int ks = 0; ks < 2; ++ks) {
        const int row = wn * 64 + 32 + ni * 16 + lr;
        const int kb = ks * 64 + hi4 * 16;
        bf[ni][ks] = *(const bf16x8*)((const char*)Bb + row * 128 + (kb ^ ((row & 7) << 4)));
      }
    if (tt < 6) STG6(3, 5, stg, k2);
    PHASE_MFMA(2)
    cur = cur == 2 ? 0 : cur + 1;
    stg = stg == 2 ? 0 : stg + 1;
  }

  const int lq = lane >> 4, lc = lane & 15;
#pragma unroll
  for (int nj = 0; nj < 4; ++nj) {
    const int n_l = wn * 64 + nj * 16 + lc;
    const float bias = b1[e * HID + n0 + n_l];
#pragma unroll
    for (int mi = 0; mi < 4; ++mi) {
#pragma unroll
      for (int j = 0; j < 4; ++j) {
        const int m_l = wm * 64 + mi * 16 + lq * 4 + j;
        float v = acc[mi][nj][j] + bias;
        h[((size_t)(e * CAP + m0 + m_l)) * HID + (n0 + n_l)] = f2bf(gelu_f(v));
      }
    }
  }
}

__global__ __launch_bounds__(512, 2)
void fc2_bf(const u16* __restrict__ h, const u16* __restrict__ w2t,
            const float* __restrict__ b2, const int* __restrict__ tok_idx,
            const float* __restrict__ expw, float* __restrict__ out) {
  const int p = blockIdx.x;
  const int l = (p & 7) * 64 + (p >> 3);         // bijective XCD remap (512 = 8*64)
  const int e  = l >> 3;
  const int mt = (l >> 1) & 3;
  const int nt = l & 1;
  const int m0 = mt * 128, n0 = nt * 256;
  const int t = threadIdx.x;
  const int lane = t & 63, wave = t >> 6;
  const int wm = wave >> 2, wn = wave & 3;

  __shared__ __align__(16) u16 AsmF[3 * A_EL];
  __shared__ __align__(16) u16 BsmF[3 * B_EL];

  const int gk = ((lane & 7) ^ (lane >> 3)) * 8;
  const int rsub = lane >> 3;

  const u16* sSrc[6];
  int dOff[6];
#pragma unroll
  for (int r = 0; r < 6; ++r) {
    const int c = r * 8 + wave;
    if (r < 2) {
      const int arow = c * 8 + rsub;
      sSrc[r] = h + ((size_t)(e * CAP + m0 + arow)) * HID + gk;
      dOff[r] = c * 512;
    } else {
      const int brow = (c - 16) * 8 + rsub;
      sSrc[r] = w2t + ((size_t)e * DIM + n0 + brow) * HID + gk;
      dOff[r] = (c - 16) * 512;
    }
  }

  f32x4 acc[4][4] = {};
  const int lr = lane & 15, hi4 = lane >> 4;

  STG6(0, 5, 0, 0);
  STG6(0, 5, 1, 64);
  int cur = 0, stg = 2;
  for (int tt = 0; tt < 16; ++tt) {              // KT = HID/64 = 16
    if (tt < 15) asm volatile("s_waitcnt vmcnt(6)" ::: "memory");
    else         asm volatile("s_waitcnt vmcnt(0)" ::: "memory");
    __builtin_amdgcn_s_barrier();
    const u16* Ab = AsmF + cur * A_EL;
    const u16* Bb = BsmF + cur * B_EL;
    const int k2 = (tt + 2) * 64;
    bf16x8 af[4][2], bf[2][2];
#pragma unroll
    for (int mi = 0; mi < 4; ++mi)
#pragma unroll
      for (int ks = 0; ks < 2; ++ks) {
        const int row = wm * 64 + mi * 16 + lr;
        const int kb = ks * 64 + hi4 * 16;
        af[mi][ks] = *(const bf16x8*)((const char*)Ab + row * 128 + (kb ^ ((row & 7) << 4)));
      }
#pragma unroll
    for (int ni = 0; ni < 2; ++ni)
#pragma unroll
      for (int ks = 0; ks < 2; ++ks) {
        const int row = wn * 64 + ni * 16 + lr;
        const int kb = ks * 64 + hi4 * 16;
        bf[ni][ks] = *(const bf16x8*)((const char*)Bb + row * 128 + (kb ^ ((row & 7) << 4)));
      }
    if (tt < 14) STG6(0, 2, stg, k2);
    PHASE_MFMA(0)
#pragma unroll
    for (int ni = 0; ni < 2; ++ni)
#pragma unroll
      for (int ks = 0; ks < 2; ++ks) {
        const int row = wn * 64 + 32 + ni * 16 + lr;
        const int kb = ks * 64 + hi4 * 16;
        bf[ni][ks] = *(const bf16x8*)((const char*)Bb + row * 128 + (kb ^ ((row & 7) << 4)));
      }
    if (tt < 14) STG6(3, 5, stg, k2);
    PHASE_MFMA(2)
    cur = cur == 2 ? 0 : cur + 1;
    stg = stg == 2 ? 0 : stg + 1;
  }

  const int lq = lane >> 4, lc = lane & 15;
  int   tokm[4][4];
  float wgt[4][4];
#pragma unroll
  for (int mi = 0; mi < 4; ++mi)
#pragma unroll
    for (int j = 0; j < 4; ++j) {
      const int m_l = wm * 64 + mi * 16 + lq * 4 + j;
      tokm[mi][j] = tok_idx[e * CAP + m0 + m_l];
      wgt[mi][j]  = expw[e * CAP + m0 + m_l];
    }
#pragma unroll
  for (int nj = 0; nj < 4; ++nj) {
    const int n_l = wn * 64 + nj * 16 + lc;
    const float bias = b2[e * DIM + n0 + n_l];
#pragma unroll
    for (int mi = 0; mi < 4; ++mi)
#pragma unroll
      for (int j = 0; j < 4; ++j) {
        float v = (acc[mi][nj][j] + bias) * wgt[mi][j];
        atomicAdd(out + (size_t)tokm[mi][j] * DIM + (n0 + n_l), v);
      }
  }
}

// ===================== fallback f32-input GEMMs (ws too small) =====================
#define SWZ(row, cb) ((cb) ^ (((((row) >> 3) ^ (row)) & 7) << 4))

__global__ __launch_bounds__(256)
void fc1_kernel(const float* __restrict__ x, const int* __restrict__ tok_idx,
                const float* __restrict__ w1, const float* __restrict__ b1,
                u16* __restrict__ h) {
  const int bx = blockIdx.x;
  const int e  = bx >> 5;
  const int mt = (bx >> 3) & 3;
  const int nt = bx & 7;
  const int m0 = mt * 128, n0 = nt * 128;
  const int t = threadIdx.x;
  const int lane = t & 63, wave = t >> 6;
  const int wm = wave >> 1, wn = wave & 1;

  __shared__ __align__(16) u16 Asm[128 * 64];
  __shared__ __align__(16) u16 Bsm[128 * 64];

  const int arq = t & 31, akq = t >> 5;
  int tokr[4];
#pragma unroll
  for (int j = 0; j < 4; ++j) tokr[j] = tok_idx[e * CAP + m0 + arq * 4 + j];
  const int nq = t & 31, kq = t >> 5;
  const float* bptr = w1 + (size_t)e * DIM * HID + n0 + nq * 4;

  f32x4 acc[4][4] = {};

  for (int k0 = 0; k0 < DIM; k0 += 64) {
    float4 av0[4], av1[4];
#pragma unroll
    for (int j = 0; j < 4; ++j) {
      const float* ap = x + (size_t)tokr[j] * DIM + k0 + akq * 8;
      av0[j] = *(const float4*)(ap);
      av1[j] = *(const float4*)(ap + 4);
    }
    float4 bv[8];
#pragma unroll
    for (int kk = 0; kk < 8; ++kk)
      bv[kk] = *(const float4*)(bptr + (size_t)(k0 + kq * 8 + kk) * HID);
    __syncthreads();
#pragma unroll
    for (int j = 0; j < 4; ++j) {
      const int row = arq * 4 + j;
      ushort4 w0, w1v;
      w0.x = f2bf(av0[j].x); w0.y = f2bf(av0[j].y); w0.z = f2bf(av0[j].z); w0.w = f2bf(av0[j].w);
      w1v.x = f2bf(av1[j].x); w1v.y = f2bf(av1[j].y); w1v.z = f2bf(av1[j].z); w1v.w = f2bf(av1[j].w);
      *(ushort4*)((char*)Asm + row * 128 + SWZ(row, (akq * 8 + 0) * 2)) = w0;
      *(ushort4*)((char*)Asm + row * 128 + SWZ(row, (akq * 8 + 4) * 2)) = w1v;
    }
#pragma unroll
    for (int g = 0; g < 2; ++g) {
#pragma unroll
      for (int j = 0; j < 4; ++j) {
        ushort4 wv;
        wv.x = f2bf(GET4(bv[g * 4 + 0], j));
        wv.y = f2bf(GET4(bv[g * 4 + 1], j));
        wv.z = f2bf(GET4(bv[g * 4 + 2], j));
        wv.w = f2bf(GET4(bv[g * 4 + 3], j));
        const int row = nq * 4 + j;
        const int cb = (kq * 8 + g * 4) * 2;
        *(ushort4*)((char*)Bsm + row * 128 + SWZ(row, cb)) = wv;
      }
    }
    __syncthreads();
#pragma unroll
    for (int ks = 0; ks < 2; ++ks) {
      bf16x8 af[4], bf[4];
#pragma unroll
      for (int mi = 0; mi < 4; ++mi) {
        const int row = wm * 64 + mi * 16 + (lane & 15);
        const int cb = ks * 64 + (lane >> 4) * 16;
        af[mi] = *(const bf16x8*)((const char*)Asm + row * 128 + SWZ(row, cb));
      }
#pragma unroll
      for (int ni = 0; ni < 4; ++ni) {
        const int row = wn * 64 + ni * 16 + (lane & 15);
        const int cb = ks * 64 + (lane >> 4) * 16;
        bf[ni] = *(const bf16x8*)((const char*)Bsm + row * 128 + SWZ(row, cb));
      }
#pragma unroll
      for (int mi = 0; mi < 4; ++mi)
#pragma unroll
        for (int ni = 0; ni < 4; ++ni)
          acc[mi][ni] = __builtin_amdgcn_mfma_f32_16x16x32_bf16(af[mi], bf[ni], acc[mi][ni], 0, 0, 0);
    }
  }
  const int lq = lane >> 4, lc = lane & 15;
#pragma unroll
  for (int ni = 0; ni < 4; ++ni) {
    const int n_l = wn * 64 + ni * 16 + lc;
    const float bias = b1[e * HID + n0 + n_l];
#pragma unroll
    for (int mi = 0; mi < 4; ++mi) {
#pragma unroll
      for (int j = 0; j < 4; ++j) {
        const int m_l = wm * 64 + mi * 16 + lq * 4 + j;
        float v = acc[mi][ni][j] + bias;
        h[((size_t)(e * CAP + m0 + m_l)) * HID + (n0 + n_l)] = f2bf(gelu_f(v));
      }
    }
  }
}

__global__ __launch_bounds__(256)
void fc2_kernel(const u16* __restrict__ h, const float* __restrict__ w2,
                const float* __restrict__ b2, const int* __restrict__ tok_idx,
                const float* __restrict__ expw, float* __restrict__ out) {
  const int bx = blockIdx.x;
  const int e  = bx >> 4;
  const int mt = (bx >> 2) & 3;
  const int nt = bx & 3;
  const int m0 = mt * 128, n0 = nt * 128;
  const int t = threadIdx.x;
  const int lane = t & 63, wave = t >> 6;
  const int wm = wave >> 1, wn = wave & 1;

  __shared__ __align__(16) u16 Asm[128 * 64];
  __shared__ __align__(16) u16 Bsm[128 * 64];

  const int arq = t & 31, akq = t >> 5;
  const u16* aptr0 = h + ((size_t)(e * CAP + m0 + arq * 4)) * HID + akq * 8;
  const int nq = t & 31, kq = t >> 5;
  const float* bptr = w2 + (size_t)e * HID * DIM + n0 + nq * 4;

  f32x4 acc[4][4] = {};

  for (int k0 = 0; k0 < HID; k0 += 64) {
    uint4 av[4];
#pragma unroll
    for (int j = 0; j < 4; ++j)
      av[j] = *(const uint4*)(aptr0 + (size_t)j * HID + k0);
    float4 bv[8];
#pragma unroll
    for (int kk = 0; kk < 8; ++kk)
      bv[kk] = *(const float4*)(bptr + (size_t)(k0 + kq * 8 + kk) * DIM);
    __syncthreads();
#pragma unroll
    for (int j = 0; j < 4; ++j) {
      const int row = arq * 4 + j;
      *(uint4*)((char*)Asm + row * 128 + SWZ(row, akq * 16)) = av[j];
    }
#pragma unroll
    for (int g = 0; g < 2; ++g) {
#pragma unroll
      for (int j = 0; j < 4; ++j) {
        ushort4 wv;
        wv.x = f2bf(GET4(bv[g * 4 + 0], j));
        wv.y = f2bf(GET4(bv[g * 4 + 1], j));
        wv.z = f2bf(GET4(bv[g * 4 + 2], j));
        wv.w = f2bf(GET4(bv[g * 4 + 3], j));
        const int row = nq * 4 + j;
        const int cb = (kq * 8 + g * 4) * 2;
        *(ushort4*)((char*)Bsm + row * 128 + SWZ(row, cb)) = wv;
      }
    }
    __syncthreads();
#pragma unroll
    for (int ks = 0; ks < 2; ++ks) {
      bf16x8 af[4], bf[4];
#pragma unroll
      for (int mi = 0; mi < 4; ++mi) {
        const int row = wm * 64 + mi * 16 + (lane & 15);
        const int cb = ks * 64 + (lane >> 4) * 16;
        af[mi] = *(const bf16x8*)((const char*)Asm + row * 128 + SWZ(row, cb));
      }
#pragma unroll
      for (int ni = 0; ni < 4; ++ni) {
        const int row = wn * 64 + ni * 16 + (lane & 15);
        const int cb = ks * 64 + (lane >> 4) * 16;
        bf[ni] = *(const bf16x8*)((const char*)Bsm + row * 128 + SWZ(row, cb));
      }
#pragma unroll
      for (int mi = 0; mi < 4; ++mi)
#pragma unroll
        for (int ni = 0; ni < 4; ++ni)
          acc[mi][ni] = __builtin_amdgcn_mfma_f32_16x16x32_bf16(af[mi], bf[ni], acc[mi][ni], 0, 0, 0);
    }
  }
  const int lq = lane >> 4, lc = lane & 15;
  int   tokm[4][4];
  float wgt[4][4];
#pragma unroll
  for (int mi = 0; mi < 4; ++mi)
#pragma unroll
    for (int j = 0; j < 4; ++j) {
      const int m_l = wm * 64 + mi * 16 + lq * 4 + j;
      tokm[mi][j] = tok_idx[e * CAP + m0 + m_l];
      wgt[mi][j]  = expw[e * CAP + m0 + m_l];
    }
#pragma unroll
  for (int ni = 0; ni < 4; ++ni) {
    const int n_l = wn * 64 + ni * 16 + lc;
    const float bias = b2[e * DIM + n0 + n_l];
#pragma unroll
    for (int mi = 0; mi < 4; ++mi)
#pragma unroll
      for (int j = 0; j < 4; ++j) {
        float v = (acc[mi][ni][j] + bias) * wgt[mi][j];
        atomicAdd(out + (size_t)tokm[mi][j] * DIM + (n0 + n_l), v);
      }
  }
}

extern "C" void kernel_launch(void* const* d_in, const int* in_sizes, int n_in,
                              void* d_out, int out_size, void* d_ws, size_t ws_size,
                              hipStream_t stream) {
  const float* x  = (const float*)d_in[0];
  const float* rw = (const float*)d_in[1];
  const float* w1 = (const float*)d_in[2];
  const float* b1 = (const float*)d_in[3];
  const float* w2 = (const float*)d_in[4];
  const float* b2 = (const float*)d_in[5];
  float* out = (float*)d_out;

  char* ws = (char*)d_ws;
  const size_t MB = 1u << 20;
  float* logits = (float*)ws;                                   // [0, 8M)
  int*   toki   = (int*)(ws + 8 * MB);                          // 128 KB
  float* ew     = (float*)(ws + 8 * MB + (128u << 10));         // 128 KB

  const size_t off_xb = 8 * MB + (256u << 10);   // 8.25M
  const size_t off_wt = off_xb + 32 * MB;        // 40.25M
  const size_t off_h  = off_wt + 64 * MB;        // 104.25M
  const size_t need   = off_h + 64 * MB;         // 168.25M
  const bool big = (ws_size >= need);

  u16* xb = big ? (u16*)(ws + off_xb) : (u16*)0;

  (void)hipMemsetAsync(d_out, 0, (size_t)out_size * sizeof(float), stream);
  router_kernel<<<dim3(512), dim3(256), 0, stream>>>(x, rw, logits, xb);
  topk_kernel<<<dim3(64), dim3(1024), 0, stream>>>(logits, toki, ew, out + (size_t)N_TOK * DIM);

  if (big) {
    u16* wt  = (u16*)(ws + off_wt);
    u16* h   = (u16*)(ws + off_h);
    transpose_cvt_kernel<<<dim3(16, 8, 64), dim3(256), 0, stream>>>(w1, wt, 512, 1024);
    fc1_bf<<<dim3(1024), dim3(512), 0, stream>>>(xb, toki, wt, b1, h);
    transpose_cvt_kernel<<<dim3(8, 16, 64), dim3(256), 0, stream>>>(w2, wt, 1024, 512);
    fc2_bf<<<dim3(512), dim3(512), 0, stream>>>(h, wt, b2, toki, ew, out);
  } else {
    u16* h = (u16*)(ws + 8 * MB + (256u << 10)); // old layout
    fc1_kernel<<<dim3(2048), dim3(256), 0, stream>>>(x, toki, w1, b1, h);
    fc2_kernel<<<dim3(1024), dim3(256), 0, stream>>>(h, w2, b2, toki, ew, out);
  }
}

// Round 13
// 388.319 us; speedup vs baseline: 1.4461x; 1.0695x over previous
//
#include <hip/hip_runtime.h>
#include <math.h>

#define N_TOK 32768
#define DIM   512
#define NEXP  64
#define HID   1024
#define CAP   512

typedef float  f32x4  __attribute__((ext_vector_type(4)));
typedef short  bf16x8 __attribute__((ext_vector_type(8)));
typedef unsigned short u16;

#define GET4(v, jj) ((jj) == 0 ? (v).x : (jj) == 1 ? (v).y : (jj) == 2 ? (v).z : (v).w)

__device__ __forceinline__ u16 f2bf(float f) {
  unsigned u = __float_as_uint(f);
  u += 0x7FFFu + ((u >> 16) & 1u);   // RNE
  return (u16)(u >> 16);
}
__device__ __forceinline__ unsigned enc_f(float f) {  // monotone f32 -> u32
  unsigned u = __float_as_uint(f);
  return (u & 0x80000000u) ? ~u : (u | 0x80000000u);
}
__device__ __forceinline__ float dec_f(unsigned k) {
  unsigned u = (k & 0x80000000u) ? (k & 0x7FFFFFFFu) : ~k;
  return __uint_as_float(u);
}
__device__ __forceinline__ void gl16(const u16* g, u16* l) {
  __builtin_amdgcn_global_load_lds(
      (const __attribute__((address_space(1))) unsigned int*)g,
      (__attribute__((address_space(3))) unsigned int*)l, 16, 0, 0);
}
// exact-enough erf (A&S 7.1.26, |eps|<=1.5e-7) -> gelu
__device__ __forceinline__ float gelu_f(float v) {
  float x = fabsf(v) * 0.70710678118654752f;
  float tt = 1.0f / (1.0f + 0.3275911f * x);
  float poly = tt * (0.254829592f + tt * (-0.284496736f + tt * (1.421413741f +
               tt * (-1.453152027f + tt * 1.061405429f))));
  float erfabs = 1.0f - poly * __expf(-x * x);
  float erfv = v >= 0.f ? erfabs : -erfabs;
  return 0.5f * v * (1.0f + erfv);
}

// ---------------- router: LDS-tiled fp32 SGEMM, 64 tok x 64 exp per block ----------------
// Also emits xb = bf16(x) as a by-product.
__global__ __launch_bounds__(256)
void router_kernel(const float* __restrict__ x, const float* __restrict__ rw,
                   float* __restrict__ logitsT, u16* __restrict__ xb) {
  __shared__ float As[32][68];   // [k][m]
  __shared__ float Bs[32][68];   // [k][e]
  const int t = threadIdx.x;
  const int n0 = blockIdx.x * 64;
  const int ty = t >> 4, tx = t & 15;
  const int am = t >> 2, akq = (t & 3) * 8;
  const int bk = t >> 3, beq = (t & 7) * 8;
  const float* xrow = x + (size_t)(n0 + am) * DIM + akq;
  u16* xbrow = xb ? (xb + (size_t)(n0 + am) * DIM + akq) : (u16*)0;
  const float* brow = rw + (size_t)bk * NEXP + beq;

  float acc[4][4] = {};
  for (int k0 = 0; k0 < DIM; k0 += 32) {
    float4 a0 = *(const float4*)(xrow + k0);
    float4 a1 = *(const float4*)(xrow + k0 + 4);
    float4 b0 = *(const float4*)(brow + (size_t)k0 * NEXP);
    float4 b1 = *(const float4*)(brow + (size_t)k0 * NEXP + 4);
    if (xbrow) {
      uint4 o;
      o.x = f2bf(a0.x) | ((unsigned)f2bf(a0.y) << 16);
      o.y = f2bf(a0.z) | ((unsigned)f2bf(a0.w) << 16);
      o.z = f2bf(a1.x) | ((unsigned)f2bf(a1.y) << 16);
      o.w = f2bf(a1.z) | ((unsigned)f2bf(a1.w) << 16);
      *(uint4*)(xbrow + k0) = o;
    }
    __syncthreads();
    As[akq + 0][am] = a0.x; As[akq + 1][am] = a0.y;
    As[akq + 2][am] = a0.z; As[akq + 3][am] = a0.w;
    As[akq + 4][am] = a1.x; As[akq + 5][am] = a1.y;
    As[akq + 6][am] = a1.z; As[akq + 7][am] = a1.w;
    *(float4*)&Bs[bk][beq] = b0;
    *(float4*)&Bs[bk][beq + 4] = b1;
    __syncthreads();
#pragma unroll
    for (int k = 0; k < 32; ++k) {
      float4 av = *(const float4*)&As[k][ty * 4];
      float4 bv = *(const float4*)&Bs[k][tx * 4];
#pragma unroll
      for (int i = 0; i < 4; ++i)
#pragma unroll
        for (int j = 0; j < 4; ++j)
          acc[i][j] += GET4(av, i) * GET4(bv, j);
    }
  }
#pragma unroll
  for (int j = 0; j < 4; ++j) {
    float4 o; o.x = acc[0][j]; o.y = acc[1][j]; o.z = acc[2][j]; o.w = acc[3][j];
    *(float4*)(logitsT + (size_t)(tx * 4 + j) * N_TOK + n0 + ty * 4) = o;
  }
}

// ------------- topk -------------
__global__ __launch_bounds__(1024)
void topk_kernel(const float* __restrict__ logitsT, int* __restrict__ tok_idx,
                 float* __restrict__ expw, float* __restrict__ auxout) {
  const int e = blockIdx.x;
  const int t = threadIdx.x;
  const float* row = logitsT + (size_t)e * N_TOK;

  unsigned key[32];          // token n = j*1024 + t
#pragma unroll
  for (int j = 0; j < 32; ++j) key[j] = enc_f(row[j * 1024 + t]);

  __shared__ unsigned ured[1024];
  __shared__ float    fred[1024];
  __shared__ unsigned hist[256];
  __shared__ unsigned sh_chosen, sh_rem, sh_x, sh_pos;

  unsigned km = 0;
#pragma unroll
  for (int j = 0; j < 32; ++j) km = key[j] > km ? key[j] : km;
  ured[t] = km;
  __syncthreads();
  for (int s = 512; s > 0; s >>= 1) {
    if (t < s) { unsigned o = ured[t + s]; if (o > ured[t]) ured[t] = o; }
    __syncthreads();
  }
  const float m = dec_f(ured[0]);

  float ssum = 0.f;
#pragma unroll
  for (int j = 0; j < 32; ++j) ssum += expf(dec_f(key[j]) - m);
  fred[t] = ssum;
  __syncthreads();
  for (int s = 512; s > 0; s >>= 1) {
    if (t < s) fred[t] += fred[t + s];
    __syncthreads();
  }
  const float invZ = 1.0f / fred[0];

  if (t == 0) sh_rem = CAP;
  __syncthreads();
  unsigned live = 0xFFFFFFFFu;
  unsigned prefix = 0;
  for (int pass = 0; pass < 4; ++pass) {
    const int shift = 24 - pass * 8;
    if (t < 256) hist[t] = 0;
    __syncthreads();
#pragma unroll
    for (int j = 0; j < 32; ++j)
      if (live & (1u << j)) atomicAdd(&hist[(key[j] >> shift) & 0xFFu], 1u);
    __syncthreads();
    if (t == 0) {
      unsigned need = sh_rem, accum = 0;
      int found = 0;
      for (int b = 255; b >= 0; --b) {
        unsigned cn = hist[b];
        if (!found) {
          if (accum + cn >= need) { sh_chosen = (unsigned)b; sh_rem = need - accum; found = 1; }
          else accum += cn;
        }
      }
    }
    __syncthreads();
    const unsigned ch = sh_chosen;
#pragma unroll
    for (int j = 0; j < 32; ++j)
      if (((key[j] >> shift) & 0xFFu) != ch) live &= ~(1u << j);
    prefix = (prefix << 8) | ch;
    __syncthreads();
  }
  const unsigned ustar = prefix;

  if (t == 0) sh_pos = 0;
  __syncthreads();
#pragma unroll
  for (int j = 0; j < 32; ++j) {
    if (key[j] > ustar) {
      unsigned p = atomicAdd(&sh_pos, 1u);
      tok_idx[e * CAP + p] = j * 1024 + t;
      expw[e * CAP + p] = expf(dec_f(key[j]) - m) * invZ;
    }
  }
  __syncthreads();
  const unsigned padv = CAP - sh_pos;

  if (t < 256) hist[t] = 0;
  __syncthreads();
#pragma unroll
  for (int j = 0; j < 32; ++j)
    if (live & (1u << j)) atomicAdd(&hist[(j * 1024 + t) >> 7], 1u);
  __syncthreads();
  if (t == 0) {
    unsigned accum = 0;
    int found = 0;
    for (int b = 0; b < 256; ++b) {
      unsigned cn = hist[b];
      if (!found) {
        if (accum + cn >= padv) { sh_chosen = (unsigned)b; sh_rem = padv - accum; found = 1; }
        else accum += cn;
      }
    }
  }
  __syncthreads();
  const unsigned hb = sh_chosen, rem = sh_rem;
  if (t < 256) hist[t] = 0;
  __syncthreads();
#pragma unroll
  for (int j = 0; j < 32; ++j)
    if (live & (1u << j)) {
      int n = j * 1024 + t;
      if ((unsigned)(n >> 7) == hb) atomicAdd(&hist[n & 127], 1u);
    }
  __syncthreads();
  if (t == 0) {
    unsigned accum = 0;
    int found = 0;
    for (int b = 0; b < 128; ++b) {
      unsigned cn = hist[b];
      if (!found) {
        if (accum + cn >= rem) { sh_x = (hb << 7) | (unsigned)b; found = 1; }
        else accum += cn;
      }
    }
  }
  __syncthreads();
  const int X = (int)sh_x;
#pragma unroll
  for (int j = 0; j < 32; ++j)
    if (live & (1u << j)) {
      int n = j * 1024 + t;
      if (n <= X) {
        unsigned p = atomicAdd(&sh_pos, 1u);
        tok_idx[e * CAP + p] = n;
        expw[e * CAP + p] = expf(dec_f(key[j]) - m) * invZ;
      }
    }
  if (e == 0 && t == 0) { auxout[0] = 2.44140625e-4f; auxout[1] = 0.015625f; }
}

// ---------------- prep: per-expert transpose+cvt: f32 [E][R][C] -> bf16 [E][C][R] ----------------
__global__ __launch_bounds__(256)
void transpose_cvt_kernel(const float* __restrict__ in, u16* __restrict__ outp,
                          int R, int C) {
  __shared__ u16 tile[64][66];
  const int e = blockIdx.z;
  const int r0 = blockIdx.y * 64, c0 = blockIdx.x * 64;
  const int t = threadIdx.x;
  {
    const int r = t >> 2, cs = (t & 3) * 16;
    const float* ip = in + ((size_t)e * R + (r0 + r)) * C + c0 + cs;
#pragma unroll
    for (int q = 0; q < 4; ++q) {
      float4 v = *(const float4*)(ip + q * 4);
      tile[r][cs + q * 4 + 0] = f2bf(v.x);
      tile[r][cs + q * 4 + 1] = f2bf(v.y);
      tile[r][cs + q * 4 + 2] = f2bf(v.z);
      tile[r][cs + q * 4 + 3] = f2bf(v.w);
    }
  }
  __syncthreads();
  {
    const int c = t >> 2, rs = (t & 3) * 16;
    u16* op = outp + ((size_t)e * C + (c0 + c)) * R + r0 + rs;
    uint4 o0, o1;
    o0.x = tile[rs + 0][c]  | ((unsigned)tile[rs + 1][c]  << 16);
    o0.y = tile[rs + 2][c]  | ((unsigned)tile[rs + 3][c]  << 16);
    o0.z = tile[rs + 4][c]  | ((unsigned)tile[rs + 5][c]  << 16);
    o0.w = tile[rs + 6][c]  | ((unsigned)tile[rs + 7][c]  << 16);
    o1.x = tile[rs + 8][c]  | ((unsigned)tile[rs + 9][c]  << 16);
    o1.y = tile[rs + 10][c] | ((unsigned)tile[rs + 11][c] << 16);
    o1.z = tile[rs + 12][c] | ((unsigned)tile[rs + 13][c] << 16);
    o1.w = tile[rs + 14][c] | ((unsigned)tile[rs + 15][c] << 16);
    *(uint4*)(op) = o0;
    *(uint4*)(op + 8) = o1;
  }
}

// ===================== bf16 GEMMs: BM128 x BN256, BK=32, 3-buf depth-2, 72KB LDS (2 blocks/CU) =====================
// Row = 32 bf16 = 64B. Swizzle: byte ^= ((row>>1)&3)<<4 (2-way bank alias = free).
// Write side: linear LDS dest, pre-swizzled global k-chunk kc = (L&3)^((L>>3)&3).
#define A_EL 4096      // 128*32 elems (8 KB)
#define B_EL 8192      // 256*32 elems (16 KB)

#define LDSW(base, row, hi4v) \
  (*(const bf16x8*)((const char*)(base) + (row) * 64 + ((((hi4v) ^ (((row) >> 1) & 3))) << 4)))

#define STG3(bs, k0) do { \
  gl16(aSrc + (k0), AsmF + (bs) * A_EL + wOff); \
  gl16(bSrc0 + (k0), BsmF + (bs) * B_EL + wOff); \
  gl16(bSrc1 + (k0), BsmF + (bs) * B_EL + wOff + 4096); \
} while (0)

__global__ __launch_bounds__(512, 4)
void fc1_bf(const u16* __restrict__ xb, const int* __restrict__ tok_idx,
            const u16* __restrict__ w1t, const float* __restrict__ b1,
            u16* __restrict__ h) {
  const int p = blockIdx.x;
  const int l = (p & 7) * 128 + (p >> 3);        // bijective XCD remap (1024 = 8*128)
  const int e  = l >> 4;
  const int mt = (l >> 2) & 3;
  const int nt = l & 3;
  const int m0 = mt * 128, n0 = nt * 256;
  const int t = threadIdx.x;
  const int lane = t & 63, wave = t >> 6;        // 8 waves
  const int wm = wave >> 2, wn = wave & 3;       // 2m x 4n, per-wave C 64x64

  __shared__ __align__(16) u16 AsmF[3 * A_EL];   // 24 KB
  __shared__ __align__(16) u16 BsmF[3 * B_EL];   // 48 KB

  const int kc = ((lane & 3) ^ ((lane >> 3) & 3)) * 8;  // pre-swizzled k elem offset
  const int rloc = lane >> 2;                    // 0..15
  const int wOff = wave * 512;                   // 16 rows x 32 elems

  const int arow = wave * 16 + rloc;             // 0..127
  const int tok = tok_idx[e * CAP + m0 + arow];
  const u16* aSrc  = xb + (size_t)tok * DIM + kc;
  const u16* bSrc0 = w1t + ((size_t)e * HID + n0 + arow) * DIM + kc;
  const u16* bSrc1 = w1t + ((size_t)e * HID + n0 + 128 + arow) * DIM + kc;

  f32x4 acc[4][4] = {};
  const int lr = lane & 15, hi4 = lane >> 4;

  STG3(0, 0);     // K-tile 0 -> buf 0
  STG3(1, 32);    // K-tile 1 -> buf 1
  int cur = 0;
  const int KT = DIM / 32;                       // 16
  for (int tt = 0; tt < KT; ++tt) {
    if (tt < KT - 1) asm volatile("s_waitcnt vmcnt(3)" ::: "memory");
    else             asm volatile("s_waitcnt vmcnt(0)" ::: "memory");
    __builtin_amdgcn_s_barrier();
    const u16* Ab = AsmF + cur * A_EL;
    const u16* Bb = BsmF + cur * B_EL;
    bf16x8 af[4], bf[4];
#pragma unroll
    for (int mi = 0; mi < 4; ++mi) af[mi] = LDSW(Ab, wm * 64 + mi * 16 + lr, hi4);
#pragma unroll
    for (int ni = 0; ni < 4; ++ni) bf[ni] = LDSW(Bb, wn * 64 + ni * 16 + lr, hi4);
    if (tt + 2 < KT) {
      const int bs = (tt + 2) % 3;
      STG3(bs, (tt + 2) * 32);
    }
    __builtin_amdgcn_s_setprio(1);
#pragma unroll
    for (int mi = 0; mi < 4; ++mi)
#pragma unroll
      for (int ni = 0; ni < 4; ++ni)
        acc[mi][ni] = __builtin_amdgcn_mfma_f32_16x16x32_bf16(af[mi], bf[ni], acc[mi][ni], 0, 0, 0);
    __builtin_amdgcn_s_setprio(0);
    __builtin_amdgcn_s_barrier();
    cur = cur == 2 ? 0 : cur + 1;
  }

  const int lq = lane >> 4, lc = lane & 15;
#pragma unroll
  for (int nj = 0; nj < 4; ++nj) {
    const int n_l = wn * 64 + nj * 16 + lc;
    const float bias = b1[e * HID + n0 + n_l];
#pragma unroll
    for (int mi = 0; mi < 4; ++mi) {
#pragma unroll
      for (int j = 0; j < 4; ++j) {
        const int m_l = wm * 64 + mi * 16 + lq * 4 + j;
        float v = acc[mi][nj][j] + bias;
        h[((size_t)(e * CAP + m0 + m_l)) * HID + (n0 + n_l)] = f2bf(gelu_f(v));
      }
    }
  }
}

__global__ __launch_bounds__(512, 4)
void fc2_bf(const u16* __restrict__ h, const u16* __restrict__ w2t,
            const float* __restrict__ b2, const int* __restrict__ tok_idx,
            const float* __restrict__ expw, float* __restrict__ out) {
  const int p = blockIdx.x;
  const int l = (p & 7) * 64 + (p >> 3);         // bijective XCD remap (512 = 8*64)
  const int e  = l >> 3;
  const int mt = (l >> 1) & 3;
  const int nt = l & 1;
  const int m0 = mt * 128, n0 = nt * 256;
  const int t = threadIdx.x;
  const int lane = t & 63, wave = t >> 6;
  const int wm = wave >> 2, wn = wave & 3;

  __shared__ __align__(16) u16 AsmF[3 * A_EL];
  __shared__ __align__(16) u16 BsmF[3 * B_EL];

  const int kc = ((lane & 3) ^ ((lane >> 3) & 3)) * 8;
  const int rloc = lane >> 2;
  const int wOff = wave * 512;

  const int arow = wave * 16 + rloc;
  const u16* aSrc  = h + ((size_t)(e * CAP + m0 + arow)) * HID + kc;
  const u16* bSrc0 = w2t + ((size_t)e * DIM + n0 + arow) * HID + kc;
  const u16* bSrc1 = w2t + ((size_t)e * DIM + n0 + 128 + arow) * HID + kc;

  f32x4 acc[4][4] = {};
  const int lr = lane & 15, hi4 = lane >> 4;

  STG3(0, 0);
  STG3(1, 32);
  int cur = 0;
  const int KT = HID / 32;                       // 32
  for (int tt = 0; tt < KT; ++tt) {
    if (tt < KT - 1) asm volatile("s_waitcnt vmcnt(3)" ::: "memory");
    else             asm volatile("s_waitcnt vmcnt(0)" ::: "memory");
    __builtin_amdgcn_s_barrier();
    const u16* Ab = AsmF + cur * A_EL;
    const u16* Bb = BsmF + cur * B_EL;
    bf16x8 af[4], bf[4];
#pragma unroll
    for (int mi = 0; mi < 4; ++mi) af[mi] = LDSW(Ab, wm * 64 + mi * 16 + lr, hi4);
#pragma unroll
    for (int ni = 0; ni < 4; ++ni) bf[ni] = LDSW(Bb, wn * 64 + ni * 16 + lr, hi4);
    if (tt + 2 < KT) {
      const int bs = (tt + 2) % 3;
      STG3(bs, (tt + 2) * 32);
    }
    __builtin_amdgcn_s_setprio(1);
#pragma unroll
    for (int mi = 0; mi < 4; ++mi)
#pragma unroll
      for (int ni = 0; ni < 4; ++ni)
        acc[mi][ni] = __builtin_amdgcn_mfma_f32_16x16x32_bf16(af[mi], bf[ni], acc[mi][ni], 0, 0, 0);
    __builtin_amdgcn_s_setprio(0);
    __builtin_amdgcn_s_barrier();
    cur = cur == 2 ? 0 : cur + 1;
  }

  const int lq = lane >> 4, lc = lane & 15;
  int   tokm[4][4];
  float wgt[4][4];
#pragma unroll
  for (int mi = 0; mi < 4; ++mi)
#pragma unroll
    for (int j = 0; j < 4; ++j) {
      const int m_l = wm * 64 + mi * 16 + lq * 4 + j;
      tokm[mi][j] = tok_idx[e * CAP + m0 + m_l];
      wgt[mi][j]  = expw[e * CAP + m0 + m_l];
    }
#pragma unroll
  for (int nj = 0; nj < 4; ++nj) {
    const int n_l = wn * 64 + nj * 16 + lc;
    const float bias = b2[e * DIM + n0 + n_l];
#pragma unroll
    for (int mi = 0; mi < 4; ++mi)
#pragma unroll
      for (int j = 0; j < 4; ++j) {
        float v = (acc[mi][nj][j] + bias) * wgt[mi][j];
        atomicAdd(out + (size_t)tokm[mi][j] * DIM + (n0 + n_l), v);
      }
  }
}

// ===================== fallback f32-input GEMMs (ws too small) =====================
#define SWZ(row, cb) ((cb) ^ (((((row) >> 3) ^ (row)) & 7) << 4))

__global__ __launch_bounds__(256)
void fc1_kernel(const float* __restrict__ x, const int* __restrict__ tok_idx,
                const float* __restrict__ w1, const float* __restrict__ b1,
                u16* __restrict__ h) {
  const int bx = blockIdx.x;
  const int e  = bx >> 5;
  const int mt = (bx >> 3) & 3;
  const int nt = bx & 7;
  const int m0 = mt * 128, n0 = nt * 128;
  const int t = threadIdx.x;
  const int lane = t & 63, wave = t >> 6;
  const int wm = wave >> 1, wn = wave & 1;

  __shared__ __align__(16) u16 Asm[128 * 64];
  __shared__ __align__(16) u16 Bsm[128 * 64];

  const int arq = t & 31, akq = t >> 5;
  int tokr[4];
#pragma unroll
  for (int j = 0; j < 4; ++j) tokr[j] = tok_idx[e * CAP + m0 + arq * 4 + j];
  const int nq = t & 31, kq = t >> 5;
  const float* bptr = w1 + (size_t)e * DIM * HID + n0 + nq * 4;

  f32x4 acc[4][4] = {};

  for (int k0 = 0; k0 < DIM; k0 += 64) {
    float4 av0[4], av1[4];
#pragma unroll
    for (int j = 0; j < 4; ++j) {
      const float* ap = x + (size_t)tokr[j] * DIM + k0 + akq * 8;
      av0[j] = *(const float4*)(ap);
      av1[j] = *(const float4*)(ap + 4);
    }
    float4 bv[8];
#pragma unroll
    for (int kk = 0; kk < 8; ++kk)
      bv[kk] = *(const float4*)(bptr + (size_t)(k0 + kq * 8 + kk) * HID);
    __syncthreads();
#pragma unroll
    for (int j = 0; j < 4; ++j) {
      const int row = arq * 4 + j;
      ushort4 w0, w1v;
      w0.x = f2bf(av0[j].x); w0.y = f2bf(av0[j].y); w0.z = f2bf(av0[j].z); w0.w = f2bf(av0[j].w);
      w1v.x = f2bf(av1[j].x); w1v.y = f2bf(av1[j].y); w1v.z = f2bf(av1[j].z); w1v.w = f2bf(av1[j].w);
      *(ushort4*)((char*)Asm + row * 128 + SWZ(row, (akq * 8 + 0) * 2)) = w0;
      *(ushort4*)((char*)Asm + row * 128 + SWZ(row, (akq * 8 + 4) * 2)) = w1v;
    }
#pragma unroll
    for (int g = 0; g < 2; ++g) {
#pragma unroll
      for (int j = 0; j < 4; ++j) {
        ushort4 wv;
        wv.x = f2bf(GET4(bv[g * 4 + 0], j));
        wv.y = f2bf(GET4(bv[g * 4 + 1], j));
        wv.z = f2bf(GET4(bv[g * 4 + 2], j));
        wv.w = f2bf(GET4(bv[g * 4 + 3], j));
        const int row = nq * 4 + j;
        const int cb = (kq * 8 + g * 4) * 2;
        *(ushort4*)((char*)Bsm + row * 128 + SWZ(row, cb)) = wv;
      }
    }
    __syncthreads();
#pragma unroll
    for (int ks = 0; ks < 2; ++ks) {
      bf16x8 af[4], bf[4];
#pragma unroll
      for (int mi = 0; mi < 4; ++mi) {
        const int row = wm * 64 + mi * 16 + (lane & 15);
        const int cb = ks * 64 + (lane >> 4) * 16;
        af[mi] = *(const bf16x8*)((const char*)Asm + row * 128 + SWZ(row, cb));
      }
#pragma unroll
      for (int ni = 0; ni < 4; ++ni) {
        const int row = wn * 64 + ni * 16 + (lane & 15);
        const int cb = ks * 64 + (lane >> 4) * 16;
        bf[ni] = *(const bf16x8*)((const char*)Bsm + row * 128 + SWZ(row, cb));
      }
#pragma unroll
      for (int mi = 0; mi < 4; ++mi)
#pragma unroll
        for (int ni = 0; ni < 4; ++ni)
          acc[mi][ni] = __builtin_amdgcn_mfma_f32_16x16x32_bf16(af[mi], bf[ni], acc[mi][ni], 0, 0, 0);
    }
  }
  const int lq = lane >> 4, lc = lane & 15;
#pragma unroll
  for (int ni = 0; ni < 4; ++ni) {
    const int n_l = wn * 64 + ni * 16 + lc;
    const float bias = b1[e * HID + n0 + n_l];
#pragma unroll
    for (int mi = 0; mi < 4; ++mi) {
#pragma unroll
      for (int j = 0; j < 4; ++j) {
        const int m_l = wm * 64 + mi * 16 + lq * 4 + j;
        float v = acc[mi][ni][j] + bias;
        h[((size_t)(e * CAP + m0 + m_l)) * HID + (n0 + n_l)] = f2bf(gelu_f(v));
      }
    }
  }
}

__global__ __launch_bounds__(256)
void fc2_kernel(const u16* __restrict__ h, const float* __restrict__ w2,
                const float* __restrict__ b2, const int* __restrict__ tok_idx,
                const float* __restrict__ expw, float* __restrict__ out) {
  const int bx = blockIdx.x;
  const int e  = bx >> 4;
  const int mt = (bx >> 2) & 3;
  const int nt = bx & 3;
  const int m0 = mt * 128, n0 = nt * 128;
  const int t = threadIdx.x;
  const int lane = t & 63, wave = t >> 6;
  const int wm = wave >> 1, wn = wave & 1;

  __shared__ __align__(16) u16 Asm[128 * 64];
  __shared__ __align__(16) u16 Bsm[128 * 64];

  const int arq = t & 31, akq = t >> 5;
  const u16* aptr0 = h + ((size_t)(e * CAP + m0 + arq * 4)) * HID + akq * 8;
  const int nq = t & 31, kq = t >> 5;
  const float* bptr = w2 + (size_t)e * HID * DIM + n0 + nq * 4;

  f32x4 acc[4][4] = {};

  for (int k0 = 0; k0 < HID; k0 += 64) {
    uint4 av[4];
#pragma unroll
    for (int j = 0; j < 4; ++j)
      av[j] = *(const uint4*)(aptr0 + (size_t)j * HID + k0);
    float4 bv[8];
#pragma unroll
    for (int kk = 0; kk < 8; ++kk)
      bv[kk] = *(const float4*)(bptr + (size_t)(k0 + kq * 8 + kk) * DIM);
    __syncthreads();
#pragma unroll
    for (int j = 0; j < 4; ++j) {
      const int row = arq * 4 + j;
      *(uint4*)((char*)Asm + row * 128 + SWZ(row, akq * 16)) = av[j];
    }
#pragma unroll
    for (int g = 0; g < 2; ++g) {
#pragma unroll
      for (int j = 0; j < 4; ++j) {
        ushort4 wv;
        wv.x = f2bf(GET4(bv[g * 4 + 0], j));
        wv.y = f2bf(GET4(bv[g * 4 + 1], j));
        wv.z = f2bf(GET4(bv[g * 4 + 2], j));
        wv.w = f2bf(GET4(bv[g * 4 + 3], j));
        const int row = nq * 4 + j;
        const int cb = (kq * 8 + g * 4) * 2;
        *(ushort4*)((char*)Bsm + row * 128 + SWZ(row, cb)) = wv;
      }
    }
    __syncthreads();
#pragma unroll
    for (int ks = 0; ks < 2; ++ks) {
      bf16x8 af[4], bf[4];
#pragma unroll
      for (int mi = 0; mi < 4; ++mi) {
        const int row = wm * 64 + mi * 16 + (lane & 15);
        const int cb = ks * 64 + (lane >> 4) * 16;
        af[mi] = *(const bf16x8*)((const char*)Asm + row * 128 + SWZ(row, cb));
      }
#pragma unroll
      for (int ni = 0; ni < 4; ++ni) {
        const int row = wn * 64 + ni * 16 + (lane & 15);
        const int cb = ks * 64 + (lane >> 4) * 16;
        bf[ni] = *(const bf16x8*)((const char*)Bsm + row * 128 + SWZ(row, cb));
      }
#pragma unroll
      for (int mi = 0; mi < 4; ++mi)
#pragma unroll
        for (int ni = 0; ni < 4; ++ni)
          acc[mi][ni] = __builtin_amdgcn_mfma_f32_16x16x32_bf16(af[mi], bf[ni], acc[mi][ni], 0, 0, 0);
    }
  }
  const int lq = lane >> 4, lc = lane & 15;
  int   tokm[4][4];
  float wgt[4][4];
#pragma unroll
  for (int mi = 0; mi < 4; ++mi)
#pragma unroll
    for (int j = 0; j < 4; ++j) {
      const int m_l = wm * 64 + mi * 16 + lq * 4 + j;
      tokm[mi][j] = tok_idx[e * CAP + m0 + m_l];
      wgt[mi][j]  = expw[e * CAP + m0 + m_l];
    }
#pragma unroll
  for (int ni = 0; ni < 4; ++ni) {
    const int n_l = wn * 64 + ni * 16 + lc;
    const float bias = b2[e * DIM + n0 + n_l];
#pragma unroll
    for (int mi = 0; mi < 4; ++mi)
#pragma unroll
      for (int j = 0; j < 4; ++j) {
        float v = (acc[mi][ni][j] + bias) * wgt[mi][j];
        atomicAdd(out + (size_t)tokm[mi][j] * DIM + (n0 + n_l), v);
      }
  }
}

extern "C" void kernel_launch(void* const* d_in, const int* in_sizes, int n_in,
                              void* d_out, int out_size, void* d_ws, size_t ws_size,
                              hipStream_t stream) {
  const float* x  = (const float*)d_in[0];
  const float* rw = (const float*)d_in[1];
  const float* w1 = (const float*)d_in[2];
  const float* b1 = (const float*)d_in[3];
  const float* w2 = (const float*)d_in[4];
  const float* b2 = (const float*)d_in[5];
  float* out = (float*)d_out;

  char* ws = (char*)d_ws;
  const size_t MB = 1u << 20;
  float* logits = (float*)ws;                                   // [0, 8M)
  int*   toki   = (int*)(ws + 8 * MB);                          // 128 KB
  float* ew     = (float*)(ws + 8 * MB + (128u << 10));         // 128 KB

  const size_t off_xb = 8 * MB + (256u << 10);   // 8.25M
  const size_t off_wt = off_xb + 32 * MB;        // 40.25M
  const size_t off_h  = off_wt + 64 * MB;        // 104.25M
  const size_t need   = off_h + 64 * MB;         // 168.25M
  const bool big = (ws_size >= need);

  u16* xb = big ? (u16*)(ws + off_xb) : (u16*)0;

  (void)hipMemsetAsync(d_out, 0, (size_t)out_size * sizeof(float), stream);
  router_kernel<<<dim3(512), dim3(256), 0, stream>>>(x, rw, logits, xb);
  topk_kernel<<<dim3(64), dim3(1024), 0, stream>>>(logits, toki, ew, out + (size_t)N_TOK * DIM);

  if (big) {
    u16* wt  = (u16*)(ws + off_wt);
    u16* h   = (u16*)(ws + off_h);
    transpose_cvt_kernel<<<dim3(16, 8, 64), dim3(256), 0, stream>>>(w1, wt, 512, 1024);
    fc1_bf<<<dim3(1024), dim3(512), 0, stream>>>(xb, toki, wt, b1, h);
    transpose_cvt_kernel<<<dim3(8, 16, 64), dim3(256), 0, stream>>>(w2, wt, 1024, 512);
    fc2_bf<<<dim3(512), dim3(512), 0, stream>>>(h, wt, b2, toki, ew, out);
  } else {
    u16* h = (u16*)(ws + 8 * MB + (256u << 10)); // old layout
    fc1_kernel<<<dim3(2048), dim3(256), 0, stream>>>(x, toki, w1, b1, h);
    fc2_kernel<<<dim3(1024), dim3(256), 0, stream>>>(h, w2, b2, toki, ew, out);
  }
}